// Round 12
// baseline (586.120 us; speedup 1.0000x reference)
//
#include <hip/hip_runtime.h>
#include <hip/hip_bf16.h>
#include <cstdio>
#include <cmath>

// Problem constants (B,T,C,NH fixed by the reference)
constexpr int   Bn = 4;
constexpr int   Tn = 2048;
constexpr int   Cn = 768;
constexpr float COEF  = 0.125f / 12.0f;   // SCALE / NH
constexpr float EPSZ  = 1e-8f;
constexpr float LNEPS = 1e-5f;
constexpr int   NTRI  = 136;              // triangular 128-tiles per batch
#define NBTC ((size_t)Bn * Tn * Cn)

typedef __bf16 bf16_t;
typedef _Float16 f16_t;
typedef bf16_t bf16x8 __attribute__((ext_vector_type(8)));
typedef bf16_t bf16x4 __attribute__((ext_vector_type(4)));
typedef f16_t  f16x8  __attribute__((ext_vector_type(8)));
typedef f16_t  f16x4  __attribute__((ext_vector_type(4)));
typedef float  f32x4  __attribute__((ext_vector_type(4)));
typedef ushort u16x8  __attribute__((ext_vector_type(8)));

// async global->LDS, 16B per lane. LDS dest is wave-uniform base + lane*16.
__device__ __forceinline__ void gload16(const void* g, void* l) {
  __builtin_amdgcn_global_load_lds(
      (const __attribute__((address_space(1))) unsigned int*)g,
      (__attribute__((address_space(3))) unsigned int*)l,
      16, 0, 0);
}

__device__ __forceinline__ ushort bf16_bits(float f) {
  bf16_t h = (bf16_t)f;
  return __builtin_bit_cast(ushort, h);
}
__device__ __forceinline__ float bits_to_f(ushort u) {
  return (float)__builtin_bit_cast(bf16_t, u);
}
__device__ __forceinline__ ushort f16bits_to_bf16bits(ushort u) {
  const float f = (float)__builtin_bit_cast(f16_t, u);
  return bf16_bits(f);
}

__device__ __forceinline__ float wave_sum(float v) {
  #pragma unroll
  for (int off = 32; off > 0; off >>= 1) v += __shfl_xor(v, off);
  return v;
}

// sv from raw zpass row-sum: zf = max(sum/Tn, EPSZ); sv = a*ps^2/(zf^2+EPSZ)
__device__ __forceinline__ float sv_of(float zraw, float a, float ps2) {
  const float zf = fmaxf(zraw * (1.0f / Tn), EPSZ);
  return a * ps2 / (zf * zf + EPSZ);
}

// E-tile XCD-aligned decode (R10): id in [0,544): x=id&7, m=id>>3, b=m/17,
// u=m%17; u<=x: (it,jm)=(x,u) else (15-x, u-x-1). Equal work per class.
__device__ __forceinline__ void etile_decode(int id, int& b, int& it, int& jm) {
  const int x = id & 7;
  const int m = id >> 3;
  b = m / 17;
  const int u = m - b * 17;
  if (u <= x) { it = x;      jm = u; }
  else        { it = 15 - x; jm = u - x - 1; }
}

// cst[] indices: 0 Lam_tk, 1 lam_tk, 2 Lam_tbar, 3 lam_tbar, 4 Lam_tk1, 5 lam_tk1, 6 = 1.0
__global__ void prep_consts(const int* kp, float* cst) {
  if (threadIdx.x == 0 && blockIdx.x == 0) {
    float tk = 1.0f + (float)(*kp);
    float tb = tk + 0.5f;
    float t1 = tk + 1.0f;
    cst[0] = tk * tk * tk; cst[1] = 1.0f / cst[0];
    cst[2] = tb * tb * tb; cst[3] = 1.0f / cst[2];
    cst[4] = t1 * t1 * t1; cst[5] = 1.0f / cst[4];
    cst[6] = 1.0f;
  }
}

// Wave-per-row LayerNorm (R11). R12: single low-precision output (fp16
// XnF only — the bf16 Xnb copy is gone; xt converts fp16->bf16 in the
// transpose). LayerNorm of (alpha*src) -> fp16, PLUS |Pi row|^2 -> aab.
// Also zeroes zbuf[row] for zpass atomics. 4 rows/block, grid 2048.
__global__ void __launch_bounds__(256) ln_sv_kernel(
    const float* __restrict__ src, const float* __restrict__ w,
    f16_t* __restrict__ outF,
    float* __restrict__ zbuf, float* __restrict__ aab,
    const float* __restrict__ Pisrc,
    const float* __restrict__ cst, int alpha_idx) {
  const int lane = threadIdx.x & 63;
  const int row  = blockIdx.x * 4 + (threadIdx.x >> 6);
  const float alpha = cst[alpha_idx];
  const float* x = src + (size_t)row * Cn;

  float4 v[3];
  float s = 0.f;
  #pragma unroll
  for (int q = 0; q < 3; ++q) {
    v[q] = *(const float4*)&x[q * 256 + lane * 4];
    v[q].x *= alpha; v[q].y *= alpha; v[q].z *= alpha; v[q].w *= alpha;
    s += v[q].x + v[q].y + v[q].z + v[q].w;
  }
  s = wave_sum(s);
  const float m = s * (1.0f / Cn);
  float vs = 0.f;
  #pragma unroll
  for (int q = 0; q < 3; ++q) {
    v[q].x -= m; v[q].y -= m; v[q].z -= m; v[q].w -= m;
    vs += v[q].x * v[q].x + v[q].y * v[q].y + v[q].z * v[q].z + v[q].w * v[q].w;
  }
  vs = wave_sum(vs);
  const float rstd = rsqrtf(vs * (1.0f / Cn) + LNEPS);

  const size_t base = (size_t)row * Cn;
  #pragma unroll
  for (int q = 0; q < 3; ++q) {
    const float4 w4 = *(const float4*)&w[q * 256 + lane * 4];
    const float f0 = v[q].x * rstd * w4.x;
    const float f1 = v[q].y * rstd * w4.y;
    const float f2 = v[q].z * rstd * w4.z;
    const float f3 = v[q].w * rstd * w4.w;
    f16x4 hf = {(f16_t)f0, (f16_t)f1, (f16_t)f2, (f16_t)f3};
    *(f16x4*)&outF[base + q * 256 + lane * 4] = hf;
  }

  // |p|^2 reduction of the Pi-side row
  const float* p = Pisrc + base;
  float a = 0.f;
  #pragma unroll
  for (int q = 0; q < 3; ++q) {
    const float4 p4 = *(const float4*)&p[q * 256 + lane * 4];
    a += p4.x * p4.x + p4.y * p4.y + p4.z * p4.z + p4.w * p4.w;
  }
  a = wave_sum(a);
  if (lane == 0) {
    aab[row] = a;
    zbuf[row] = 0.0f;
  }
}

// Transpose XnF(fp16) [b][s][c] -> XT [b][c][s] (bf16), converting
// fp16->bf16 on the load side (R12: Xnb buffer eliminated).
// grid (Tn/64, Cn/64, Bn).
__global__ void __launch_bounds__(256) xt_kernel(
    const ushort* __restrict__ XhF, ushort* __restrict__ XT) {
  const int b = blockIdx.z;
  const int s0 = blockIdx.x * 64, c0 = blockIdx.y * 64;
  const int tid = threadIdx.x;
  __shared__ ushort t[64][68];
  const ushort* src = XhF + (size_t)b * Tn * Cn;
  ushort* dst = XT + (size_t)b * Cn * Tn;
  #pragma unroll
  for (int p = 0; p < 4; ++p) {
    const int r = p * 16 + (tid >> 4);
    const int c = (tid & 15) * 4;
    const ushort4 v = *(const ushort4*)&src[(size_t)(s0 + r) * Cn + c0 + c];
    ushort4 bv;
    bv.x = f16bits_to_bf16bits(v.x);
    bv.y = f16bits_to_bf16bits(v.y);
    bv.z = f16bits_to_bf16bits(v.z);
    bv.w = f16bits_to_bf16bits(v.w);
    *(ushort4*)&t[r][c] = bv;
  }
  __syncthreads();
  #pragma unroll
  for (int p = 0; p < 4; ++p) {
    const int cc = p * 16 + (tid >> 4);
    const int ss = (tid & 15) * 4;
    ushort4 o;
    o.x = t[ss + 0][cc]; o.y = t[ss + 1][cc];
    o.z = t[ss + 2][cc]; o.w = t[ss + 3][cc];
    *(ushort4*)&dst[(size_t)(c0 + cc) * Tn + s0 + ss] = o;
  }
}

// Causal gram, 128x128 tiles (R9), XCD-aligned 1D grid 544 (R10).
// R12: BK=128 chunks (6 instead of 12) — halves the barrier-drain count
// at constant staged bytes ("more work per drain", the R9 mechanism).
// LDS 64 KB; occupancy stays grid-limited (544/256 = 2.1 <= 2-block cap).
// E = exp(clip(S*COEF)) stored single-bf16 pair-packed. Row sums ->
// atomicAdd zbuf. block 256, acc[4][4].
__global__ void __launch_bounds__(256) zpass_mfma(
    const f16_t* __restrict__ XnF,
    ushort* __restrict__ Ehp, float* __restrict__ zbuf) {
  int b, it, jm;
  etile_decode(blockIdx.x, b, it, jm);
  const int l = it * (it + 1) / 2 + jm;
  const int t0 = it * 128, s0 = jm * 128;

  const int tid  = threadIdx.x;
  const int lane = tid & 63;
  const int wv   = tid >> 6;
  const int wr   = wv >> 1, wc = wv & 1;     // wave covers 64t x 64s
  const int quad = lane >> 4, l15 = lane & 15;

  const f16_t* XbF = XnF + (size_t)b * Tn * Cn;
  ushort* EhT = Ehp + ((size_t)b * NTRI + l) * 16384;

  __shared__ f16_t Af[4][128 * 32];   // 32 KB
  __shared__ f16_t Bf[4][128 * 32];   // 32 KB

  const int srow = lane >> 2;                // 0..15
  const int scol = (lane & 3) * 8;

  f32x4 acc[4][4] = {};

  for (int c0 = 0; c0 < Cn; c0 += 128) {
    __syncthreads();                 // protect LDS while prev chunk still read
    #pragma unroll
    for (int h = 0; h < 4; ++h) {
      const int cb = c0 + h * 32;
      const int rb0 = wv * 16, rb1 = 64 + wv * 16;
      gload16(XbF + (size_t)(t0 + rb0 + srow) * Cn + cb + scol, Af[h] + rb0 * 32);
      gload16(XbF + (size_t)(t0 + rb1 + srow) * Cn + cb + scol, Af[h] + rb1 * 32);
      gload16(XbF + (size_t)(s0 + rb0 + srow) * Cn + cb + scol, Bf[h] + rb0 * 32);
      gload16(XbF + (size_t)(s0 + rb1 + srow) * Cn + cb + scol, Bf[h] + rb1 * 32);
    }
    __syncthreads();                 // drain vmcnt + all slabs present

    #pragma unroll
    for (int h = 0; h < 4; ++h) {
      f16x8 af[4], bf[4];
      #pragma unroll
      for (int i = 0; i < 4; ++i)
        af[i] = *(const f16x8*)&Af[h][(wr * 64 + i * 16 + l15) * 32 + quad * 8];
      #pragma unroll
      for (int j = 0; j < 4; ++j)
        bf[j] = *(const f16x8*)&Bf[h][(wc * 64 + j * 16 + l15) * 32 + quad * 8];
      #pragma unroll
      for (int i = 0; i < 4; ++i)
        #pragma unroll
        for (int j = 0; j < 4; ++j)
          acc[i][j] = __builtin_amdgcn_mfma_f32_16x16x32_f16(af[i], bf[j], acc[i][j], 0, 0, 0);
    }
  }

  float zacc[4][4];
  #pragma unroll
  for (int i = 0; i < 4; ++i)
    #pragma unroll
    for (int r = 0; r < 4; ++r) zacc[i][r] = 0.0f;

  #pragma unroll
  for (int i = 0; i < 4; ++i) {
    #pragma unroll
    for (int j = 0; j < 4; ++j) {
      const int inCol = wc * 64 + j * 16 + l15;
      const int gcol  = s0 + inCol;
      #pragma unroll
      for (int r = 0; r < 4; ++r) {
        const int rowL = wr * 64 + i * 16 + quad * 4 + r;
        float sV = acc[i][j][r] * COEF;
        sV = fminf(fmaxf(sV, -60.f), 60.f);
        const float e = (gcol <= t0 + rowL) ? __expf(sV) : 0.f;
        const float pe = __shfl_xor(e, 1);
        if ((lane & 1) == 0) {
          const uint pk = (uint)bf16_bits(e) | ((uint)bf16_bits(pe) << 16);
          *(uint*)&EhT[rowL * 128 + inCol] = pk;
        }
        zacc[i][r] += e;
      }
    }
  }
  #pragma unroll
  for (int i = 0; i < 4; ++i)
    #pragma unroll
    for (int r = 0; r < 4; ++r) {
      float v = zacc[i][r];
      v += __shfl_xor(v, 1);
      v += __shfl_xor(v, 2);
      v += __shfl_xor(v, 4);
      v += __shfl_xor(v, 8);
      if (l15 == 0)
        atomicAdd(&zbuf[b * Tn + t0 + wr * 64 + i * 16 + quad * 4 + r], v);
    }
}

// In-place W-build: E[t,s] *= (sv[t] + sv[s] - 2), packed single-bf16 tiles.
// sv computed inline from raw zbuf + aab (R8). 1D grid 544, XCD-aligned
// decode (R10).
__global__ void __launch_bounds__(256) wbuild_kernel(
    ushort* __restrict__ Ehp, const float* __restrict__ zbuf,
    const float* __restrict__ aab, const float* __restrict__ cst, int ps_idx) {
  int b, it, st;
  etile_decode(blockIdx.x, b, it, st);
  const int tri = it * (it + 1) / 2 + st;
  ushort* EhT = Ehp + ((size_t)b * NTRI + tri) * 16384;
  const float ps = cst[ps_idx];
  const float ps2 = ps * ps;

  const int tid = threadIdx.x;
  __shared__ float scol[128];
  if (tid < 128) {
    const int i = b * Tn + st * 128 + tid;
    scol[tid] = sv_of(zbuf[i], aab[i], ps2);
  }
  __syncthreads();

  const int r  = tid >> 1;            // 0..127
  const int ch = (tid & 1) * 64;      // col half
  const int irow = b * Tn + it * 128 + r;
  const float svt2 = sv_of(zbuf[irow], aab[irow], ps2) - 2.0f;
  const int base = r * 128 + ch;
  #pragma unroll
  for (int v = 0; v < 8; ++v) {
    u16x8 h8 = *(const u16x8*)&EhT[base + v * 8];
    u16x8 nh;
    #pragma unroll
    for (int q = 0; q < 8; ++q) {
      const float w = bits_to_f(h8[q]) * (svt2 + scol[ch + v * 8 + q]);
      nh[q] = bf16_bits(w);
    }
    *(u16x8*)&EhT[base + v * 8] = nh;
  }
}

// core GEMM + fused elementwise epilogues. K=64 double-slab chunks, R0
// 2-barrier loop, 128t x 64c tile, grid 768. R7 XCD-paired balanced
// swizzle. z finalization inline (R8) — zb holds RAW row sums.
template <int MODE>
__global__ void __launch_bounds__(256) corepass_mfma(
    const ushort* __restrict__ Whp, const ushort* __restrict__ XT,
    const float* src, float* dst,
    const float* __restrict__ cst, int ss_idx, int lam_idx,
    float* eA, float* eB, float* eC, float* eD,
    const float* __restrict__ zb, int vel_idx, float rc, float rs) {
  const int id = blockIdx.x;
  const int x  = id & 7;                 // XCD class
  const int n  = id >> 3;                // 0..95
  const int k  = n / 12;                 // strip 0..7 within class
  const int ic = n - k * 12;             // 0..11
  const int b  = k & 3;
  const int it = (k >> 2) ? x : (15 - x);   // big strips first
  const int t0 = it * 128, c0 = ic * 64;

  const int tid  = threadIdx.x;
  const int lane = tid & 63;
  const int wv   = tid >> 6;
  const int wr   = wv >> 1, wc = wv & 1;   // wave covers 64t x 32c
  const int quad = lane >> 4, l15 = lane & 15;

  const ushort* WhB = Whp + (size_t)b * NTRI * 16384;
  const ushort* XTb = XT + (size_t)b * Cn * Tn;

  __shared__ ushort Ah[2][128 * 32];   // W slabs  (16 KB)
  __shared__ ushort Bh[2][64 * 32];    // X^T slabs (8 KB)

  const int srow = lane >> 2;
  const int scol = (lane & 3) * 8;
  const int triBase = it * (it + 1) / 2;

  f32x4 acc[4][2] = {};
  const int chunks = (it + 1) * 2;           // 64-k chunks
  for (int kc = 0; kc < chunks; ++kc) {
    const int ss0 = kc * 64;
    const int stile = kc >> 1, soff = (kc & 1) * 64;
    const ushort* tileB = WhB + (size_t)(triBase + stile) * 16384 + soff;

    __syncthreads();                 // prev chunk's LDS reads done
    #pragma unroll
    for (int h = 0; h < 2; ++h) {
      const ushort* tileH = tileB + h * 32;
      const int rb0 = wv * 16, rb1 = 64 + wv * 16;
      gload16(tileH + (size_t)(rb0 + srow) * 128 + scol, Ah[h] + rb0 * 32);
      gload16(tileH + (size_t)(rb1 + srow) * 128 + scol, Ah[h] + rb1 * 32);
      gload16(XTb + (size_t)(c0 + wv * 16 + srow) * Tn + ss0 + h * 32 + scol,
              Bh[h] + wv * 16 * 32);
    }
    __syncthreads();                 // drain vmcnt

    #pragma unroll
    for (int h = 0; h < 2; ++h) {
      bf16x8 ah[4], bh[2];
      #pragma unroll
      for (int i = 0; i < 4; ++i)
        ah[i] = *(const bf16x8*)&Ah[h][(wr * 64 + i * 16 + l15) * 32 + quad * 8];
      #pragma unroll
      for (int j = 0; j < 2; ++j)
        bh[j] = *(const bf16x8*)&Bh[h][(wc * 32 + j * 16 + l15) * 32 + quad * 8];
      #pragma unroll
      for (int i = 0; i < 4; ++i)
        #pragma unroll
        for (int j = 0; j < 2; ++j)
          acc[i][j] = __builtin_amdgcn_mfma_f32_16x16x32_bf16(ah[i], bh[j], acc[i][j], 0, 0, 0);
    }
  }

  const float coef = 0.5f * cst[lam_idx] * (1.0f / (2.0f * Tn));
  const float ssc = cst[ss_idx];
  const float vs = 0.5f * cst[vel_idx];
  #pragma unroll
  for (int i = 0; i < 4; ++i) {
    #pragma unroll
    for (int j = 0; j < 2; ++j) {
      const int col = c0 + wc * 32 + j * 16 + l15;
      #pragma unroll
      for (int r = 0; r < 4; ++r) {
        const int row = t0 + wr * 64 + i * 16 + quad * 4 + r;
        const size_t off = ((size_t)b * Tn + row) * Cn + col;
        const float srcv = src[off];
        const float d = srcv * ssc + coef * acc[i][j][r];
        if (MODE == 0) {
          const float z = fmaxf(zb[b * Tn + row] * (1.0f / Tn), EPSZ);
          dst[off] = d;
          eC[off] = eA[off] + vs * srcv / z;
        } else if (MODE == 1) {
          const float z = fmaxf(zb[b * Tn + row] * (1.0f / Tn), EPSZ);
          const float po = eB[off];
          const float xo = eA[off] + vs * po / z;
          const float bx = eC[off];
          const float dX = xo - bx, dPi = po - d;
          const float sX = xo + bx, sPi = po + d;
          eD[off]  = 0.5f * (sX + rc * dX + rs * dPi);   // Xo
          eB[off]  = 0.5f * (sPi - rs * dX + rc * dPi);  // Po
          eC[off]  = 0.5f * (sX - rc * dX - rs * dPi);   // bX
          dst[off] = 0.5f * (sPi + rs * dX - rc * dPi);  // bPi
        } else if (MODE == 2) {
          const float z = fmaxf(zb[b * Tn + row] * (1.0f / Tn), EPSZ);
          dst[off] = d;
          eA[off] = eA[off] + vs * eB[off] / z;
        } else {
          dst[off] = d;
        }
      }
    }
  }
}

// Wave-per-row final LayerNorm (fp32 out, in-place capable) (R11).
__global__ void __launch_bounds__(256) ln_f32_kernel(
    const float* src, const float* __restrict__ w,
    float* dst, const float* __restrict__ cst, int alpha_idx) {
  const int lane = threadIdx.x & 63;
  const int row  = blockIdx.x * 4 + (threadIdx.x >> 6);
  const float alpha = cst[alpha_idx];
  const float* x = src + (size_t)row * Cn;

  float4 v[3];
  float s = 0.f;
  #pragma unroll
  for (int q = 0; q < 3; ++q) {
    v[q] = *(const float4*)&x[q * 256 + lane * 4];
    v[q].x *= alpha; v[q].y *= alpha; v[q].z *= alpha; v[q].w *= alpha;
    s += v[q].x + v[q].y + v[q].z + v[q].w;
  }
  s = wave_sum(s);
  const float m = s * (1.0f / Cn);
  float vs = 0.f;
  #pragma unroll
  for (int q = 0; q < 3; ++q) {
    v[q].x -= m; v[q].y -= m; v[q].z -= m; v[q].w -= m;
    vs += v[q].x * v[q].x + v[q].y * v[q].y + v[q].z * v[q].z + v[q].w * v[q].w;
  }
  vs = wave_sum(vs);
  const float rstd = rsqrtf(vs * (1.0f / Cn) + LNEPS);

  float* y = dst + (size_t)row * Cn;
  #pragma unroll
  for (int q = 0; q < 3; ++q) {
    const float4 w4 = *(const float4*)&w[q * 256 + lane * 4];
    float4 o;
    o.x = v[q].x * rstd * w4.x;
    o.y = v[q].y * rstd * w4.y;
    o.z = v[q].z * rstd * w4.z;
    o.w = v[q].w * rstd * w4.w;
    *(float4*)&y[q * 256 + lane * 4] = o;
  }
}

extern "C" void kernel_launch(void* const* d_in, const int* in_sizes, int n_in,
                              void* d_out, int out_size, void* d_ws, size_t ws_size,
                              hipStream_t stream) {
  (void)in_sizes; (void)n_in; (void)out_size;
  const float* Xk  = (const float*)d_in[0];
  const float* Pk  = (const float*)d_in[1];
  const float* lw  = (const float*)d_in[2];
  const float* lvw = (const float*)d_in[3];
  const int*   kp  = (const int*)d_in[4];

  float* Xo = (float*)d_out;        // X state in d_out[0:BTC]
  float* Po = Xo + NBTC;            // Pi state in d_out[BTC:2BTC]

  char* wp = (char*)d_ws;
  float*  bX  = (float*)wp;  wp += NBTC * sizeof(float);
  float*  bPi = (float*)wp;  wp += NBTC * sizeof(float);
  f16_t*  XnF = (f16_t*)wp;  wp += NBTC * sizeof(f16_t);
  ushort* Ehp = (ushort*)wp; wp += (size_t)Bn * NTRI * 16384 * sizeof(ushort);
  ushort* XTh = (ushort*)wp; wp += NBTC * sizeof(ushort);
  float*  zb  = (float*)wp;  wp += (size_t)Bn * Tn * sizeof(float);
  float*  aab = (float*)wp;  wp += (size_t)Bn * Tn * sizeof(float);
  float*  cst = (float*)wp;  wp += 256;
  const size_t need = (size_t)(wp - (char*)d_ws);
  if (ws_size < need) {
    fprintf(stderr, "[kernel] ws too small: %zu < %zu\n", ws_size, need);
    return;
  }

  const dim3 b256(256);
  const dim3 gLN(Bn * Tn / 4);               // wave-per-row, 4 rows/block
  const dim3 gXT(Tn / 64, Cn / 64, Bn);      // (32,12,4)
  const dim3 gZ(544);                        // XCD-aligned E-tile decode
  const dim3 gW(544);                        // same decode (no dead blocks)
  const dim3 gCore(768);                     // XCD-paired balanced swizzle
  const float rc = (float)cos(2.0), rs = (float)sin(2.0);   // theta = 2*XI*h

  prep_consts<<<1, 1, 0, stream>>>(kp, cst);

  // ---- Stage A: X-side = Xk, p = Pk (lam*Lam = 1) ----
  ln_sv_kernel<<<gLN, b256, 0, stream>>>(Xk, lw, XnF, zb, aab, Pk, cst, 6);
  xt_kernel<<<gXT, b256, 0, stream>>>((const ushort*)XnF, XTh);
  zpass_mfma<<<gZ, b256, 0, stream>>>(XnF, Ehp, zb);
  wbuild_kernel<<<gW, b256, 0, stream>>>(Ehp, zb, aab, cst, 6);
  corepass_mfma<0><<<gCore, b256, 0, stream>>>(Ehp, XTh, Pk, Po, cst, 0, 0,
      (float*)Xk, nullptr, bX, nullptr, zb, 6, rc, rs);

  // ---- Stage B: X-side = bX, Pi-side = Po; fused velupd-B + rotation ----
  ln_sv_kernel<<<gLN, b256, 0, stream>>>(bX, lw, XnF, zb, aab, Po, cst, 6);
  xt_kernel<<<gXT, b256, 0, stream>>>((const ushort*)XnF, XTh);
  zpass_mfma<<<gZ, b256, 0, stream>>>(XnF, Ehp, zb);
  wbuild_kernel<<<gW, b256, 0, stream>>>(Ehp, zb, aab, cst, 3);
  corepass_mfma<1><<<gCore, b256, 0, stream>>>(Ehp, XTh, Pk, bPi, cst, 0, 2,
      (float*)Xk, Po, bX, Xo, zb, 3, rc, rs);

  // ---- Stage C: X-side = bX, Pi-side = Po; fused velupd-C ----
  ln_sv_kernel<<<gLN, b256, 0, stream>>>(bX, lw, XnF, zb, aab, Po, cst, 6);
  xt_kernel<<<gXT, b256, 0, stream>>>((const ushort*)XnF, XTh);
  zpass_mfma<<<gZ, b256, 0, stream>>>(XnF, Ehp, zb);
  wbuild_kernel<<<gW, b256, 0, stream>>>(Ehp, zb, aab, cst, 3);
  corepass_mfma<2><<<gCore, b256, 0, stream>>>(Ehp, XTh, bPi, bPi, cst, 6, 2,
      Xo, Po, nullptr, nullptr, zb, 3, rc, rs);

  // ---- Stage D: X-side = Xo, p = lam_tk1*bPi ----
  ln_sv_kernel<<<gLN, b256, 0, stream>>>(Xo, lw, XnF, zb, aab, bPi, cst, 6);
  xt_kernel<<<gXT, b256, 0, stream>>>((const ushort*)XnF, XTh);
  zpass_mfma<<<gZ, b256, 0, stream>>>(XnF, Ehp, zb);
  wbuild_kernel<<<gW, b256, 0, stream>>>(Ehp, zb, aab, cst, 5);
  corepass_mfma<3><<<gCore, b256, 0, stream>>>(Ehp, XTh, Po, Po, cst, 6, 4,
      nullptr, nullptr, nullptr, nullptr, zb, 6, rc, rs);

  // ---- Final: Pk1 = LN(lam_tk1 * Pi) * ln_v_w (in place on Po) ----
  ln_f32_kernel<<<gLN, b256, 0, stream>>>(Po, lvw, Po, cst, 5);
}

// Round 13
// 540.311 us; speedup vs baseline: 1.0848x; 1.0848x over previous
//
#include <hip/hip_runtime.h>
#include <hip/hip_bf16.h>
#include <cstdio>
#include <cmath>

// Problem constants (B,T,C,NH fixed by the reference)
constexpr int   Bn = 4;
constexpr int   Tn = 2048;
constexpr int   Cn = 768;
constexpr float COEF  = 0.125f / 12.0f;   // SCALE / NH
constexpr float EPSZ  = 1e-8f;
constexpr float LNEPS = 1e-5f;
constexpr int   NTRI  = 136;              // triangular 128-tiles per batch
#define NBTC ((size_t)Bn * Tn * Cn)

typedef __bf16 bf16_t;
typedef _Float16 f16_t;
typedef bf16_t bf16x8 __attribute__((ext_vector_type(8)));
typedef bf16_t bf16x4 __attribute__((ext_vector_type(4)));
typedef f16_t  f16x8  __attribute__((ext_vector_type(8)));
typedef f16_t  f16x4  __attribute__((ext_vector_type(4)));
typedef float  f32x4  __attribute__((ext_vector_type(4)));
typedef ushort u16x8  __attribute__((ext_vector_type(8)));

// async global->LDS, 16B per lane. LDS dest is wave-uniform base + lane*16.
__device__ __forceinline__ void gload16(const void* g, void* l) {
  __builtin_amdgcn_global_load_lds(
      (const __attribute__((address_space(1))) unsigned int*)g,
      (__attribute__((address_space(3))) unsigned int*)l,
      16, 0, 0);
}

__device__ __forceinline__ ushort bf16_bits(float f) {
  bf16_t h = (bf16_t)f;
  return __builtin_bit_cast(ushort, h);
}
__device__ __forceinline__ float bits_to_f(ushort u) {
  return (float)__builtin_bit_cast(bf16_t, u);
}
__device__ __forceinline__ ushort f16bits_to_bf16bits(ushort u) {
  const float f = (float)__builtin_bit_cast(f16_t, u);
  return bf16_bits(f);
}

__device__ __forceinline__ float wave_sum(float v) {
  #pragma unroll
  for (int off = 32; off > 0; off >>= 1) v += __shfl_xor(v, off);
  return v;
}

// sv from raw zpass row-sum: zf = max(sum/Tn, EPSZ); sv = a*ps^2/(zf^2+EPSZ)
__device__ __forceinline__ float sv_of(float zraw, float a, float ps2) {
  const float zf = fmaxf(zraw * (1.0f / Tn), EPSZ);
  return a * ps2 / (zf * zf + EPSZ);
}

// E-tile XCD-aligned decode (R10): id in [0,544): x=id&7, m=id>>3, b=m/17,
// u=m%17; u<=x: (it,jm)=(x,u) else (15-x, u-x-1). Equal work per class.
__device__ __forceinline__ void etile_decode(int id, int& b, int& it, int& jm) {
  const int x = id & 7;
  const int m = id >> 3;
  b = m / 17;
  const int u = m - b * 17;
  if (u <= x) { it = x;      jm = u; }
  else        { it = 15 - x; jm = u - x - 1; }
}

// cst[] indices: 0 Lam_tk, 1 lam_tk, 2 Lam_tbar, 3 lam_tbar, 4 Lam_tk1, 5 lam_tk1, 6 = 1.0
__global__ void prep_consts(const int* kp, float* cst) {
  if (threadIdx.x == 0 && blockIdx.x == 0) {
    float tk = 1.0f + (float)(*kp);
    float tb = tk + 0.5f;
    float t1 = tk + 1.0f;
    cst[0] = tk * tk * tk; cst[1] = 1.0f / cst[0];
    cst[2] = tb * tb * tb; cst[3] = 1.0f / cst[2];
    cst[4] = t1 * t1 * t1; cst[5] = 1.0f / cst[4];
    cst[6] = 1.0f;
  }
}

// Wave-per-row LayerNorm (R11) with single fp16 output (R12-kept: the
// bf16 Xnb copy is gone; xt converts fp16->bf16 in the transpose).
// LayerNorm of (alpha*src) -> fp16, PLUS |Pi row|^2 -> aab.
// Also zeroes zbuf[row] for zpass atomics. 4 rows/block, grid 2048.
__global__ void __launch_bounds__(256) ln_sv_kernel(
    const float* __restrict__ src, const float* __restrict__ w,
    f16_t* __restrict__ outF,
    float* __restrict__ zbuf, float* __restrict__ aab,
    const float* __restrict__ Pisrc,
    const float* __restrict__ cst, int alpha_idx) {
  const int lane = threadIdx.x & 63;
  const int row  = blockIdx.x * 4 + (threadIdx.x >> 6);
  const float alpha = cst[alpha_idx];
  const float* x = src + (size_t)row * Cn;

  float4 v[3];
  float s = 0.f;
  #pragma unroll
  for (int q = 0; q < 3; ++q) {
    v[q] = *(const float4*)&x[q * 256 + lane * 4];
    v[q].x *= alpha; v[q].y *= alpha; v[q].z *= alpha; v[q].w *= alpha;
    s += v[q].x + v[q].y + v[q].z + v[q].w;
  }
  s = wave_sum(s);
  const float m = s * (1.0f / Cn);
  float vs = 0.f;
  #pragma unroll
  for (int q = 0; q < 3; ++q) {
    v[q].x -= m; v[q].y -= m; v[q].z -= m; v[q].w -= m;
    vs += v[q].x * v[q].x + v[q].y * v[q].y + v[q].z * v[q].z + v[q].w * v[q].w;
  }
  vs = wave_sum(vs);
  const float rstd = rsqrtf(vs * (1.0f / Cn) + LNEPS);

  const size_t base = (size_t)row * Cn;
  #pragma unroll
  for (int q = 0; q < 3; ++q) {
    const float4 w4 = *(const float4*)&w[q * 256 + lane * 4];
    const float f0 = v[q].x * rstd * w4.x;
    const float f1 = v[q].y * rstd * w4.y;
    const float f2 = v[q].z * rstd * w4.z;
    const float f3 = v[q].w * rstd * w4.w;
    f16x4 hf = {(f16_t)f0, (f16_t)f1, (f16_t)f2, (f16_t)f3};
    *(f16x4*)&outF[base + q * 256 + lane * 4] = hf;
  }

  // |p|^2 reduction of the Pi-side row
  const float* p = Pisrc + base;
  float a = 0.f;
  #pragma unroll
  for (int q = 0; q < 3; ++q) {
    const float4 p4 = *(const float4*)&p[q * 256 + lane * 4];
    a += p4.x * p4.x + p4.y * p4.y + p4.z * p4.z + p4.w * p4.w;
  }
  a = wave_sum(a);
  if (lane == 0) {
    aab[row] = a;
    zbuf[row] = 0.0f;
  }
}

// Transpose XnF(fp16) [b][s][c] -> XT [b][c][s] (bf16), converting
// fp16->bf16 on the load side (Xnb buffer eliminated).
// grid (Tn/64, Cn/64, Bn).
__global__ void __launch_bounds__(256) xt_kernel(
    const ushort* __restrict__ XhF, ushort* __restrict__ XT) {
  const int b = blockIdx.z;
  const int s0 = blockIdx.x * 64, c0 = blockIdx.y * 64;
  const int tid = threadIdx.x;
  __shared__ ushort t[64][68];
  const ushort* src = XhF + (size_t)b * Tn * Cn;
  ushort* dst = XT + (size_t)b * Cn * Tn;
  #pragma unroll
  for (int p = 0; p < 4; ++p) {
    const int r = p * 16 + (tid >> 4);
    const int c = (tid & 15) * 4;
    const ushort4 v = *(const ushort4*)&src[(size_t)(s0 + r) * Cn + c0 + c];
    ushort4 bv;
    bv.x = f16bits_to_bf16bits(v.x);
    bv.y = f16bits_to_bf16bits(v.y);
    bv.z = f16bits_to_bf16bits(v.z);
    bv.w = f16bits_to_bf16bits(v.w);
    *(ushort4*)&t[r][c] = bv;
  }
  __syncthreads();
  #pragma unroll
  for (int p = 0; p < 4; ++p) {
    const int cc = p * 16 + (tid >> 4);
    const int ss = (tid & 15) * 4;
    ushort4 o;
    o.x = t[ss + 0][cc]; o.y = t[ss + 1][cc];
    o.z = t[ss + 2][cc]; o.w = t[ss + 3][cc];
    *(ushort4*)&dst[(size_t)(c0 + cc) * Tn + s0 + ss] = o;
  }
}

// Causal gram, 128x128 tiles (R9), XCD-aligned 1D grid 544 (R10).
// R13: REVERTED to BK=64 / 32 KB LDS — R12's BK=128 replayed the m132
// failure (64 KB LDS caps 2 blocks/CU, grid needs 2.1 -> tail serial).
// E = exp(clip(S*COEF)) stored single-bf16 pair-packed. Row sums ->
// atomicAdd zbuf. block 256, acc[4][4].
__global__ void __launch_bounds__(256) zpass_mfma(
    const f16_t* __restrict__ XnF,
    ushort* __restrict__ Ehp, float* __restrict__ zbuf) {
  int b, it, jm;
  etile_decode(blockIdx.x, b, it, jm);
  const int l = it * (it + 1) / 2 + jm;
  const int t0 = it * 128, s0 = jm * 128;

  const int tid  = threadIdx.x;
  const int lane = tid & 63;
  const int wv   = tid >> 6;
  const int wr   = wv >> 1, wc = wv & 1;     // wave covers 64t x 64s
  const int quad = lane >> 4, l15 = lane & 15;

  const f16_t* XbF = XnF + (size_t)b * Tn * Cn;
  ushort* EhT = Ehp + ((size_t)b * NTRI + l) * 16384;

  __shared__ f16_t Af[2][128 * 32];   // 16 KB
  __shared__ f16_t Bf[2][128 * 32];   // 16 KB

  const int srow = lane >> 2;                // 0..15
  const int scol = (lane & 3) * 8;

  f32x4 acc[4][4] = {};

  for (int c0 = 0; c0 < Cn; c0 += 64) {
    __syncthreads();                 // protect LDS while prev chunk still read
    #pragma unroll
    for (int h = 0; h < 2; ++h) {
      const int cb = c0 + h * 32;
      const int rb0 = wv * 16, rb1 = 64 + wv * 16;
      gload16(XbF + (size_t)(t0 + rb0 + srow) * Cn + cb + scol, Af[h] + rb0 * 32);
      gload16(XbF + (size_t)(t0 + rb1 + srow) * Cn + cb + scol, Af[h] + rb1 * 32);
      gload16(XbF + (size_t)(s0 + rb0 + srow) * Cn + cb + scol, Bf[h] + rb0 * 32);
      gload16(XbF + (size_t)(s0 + rb1 + srow) * Cn + cb + scol, Bf[h] + rb1 * 32);
    }
    __syncthreads();                 // drain vmcnt + all slabs present

    #pragma unroll
    for (int h = 0; h < 2; ++h) {
      f16x8 af[4], bf[4];
      #pragma unroll
      for (int i = 0; i < 4; ++i)
        af[i] = *(const f16x8*)&Af[h][(wr * 64 + i * 16 + l15) * 32 + quad * 8];
      #pragma unroll
      for (int j = 0; j < 4; ++j)
        bf[j] = *(const f16x8*)&Bf[h][(wc * 64 + j * 16 + l15) * 32 + quad * 8];
      #pragma unroll
      for (int i = 0; i < 4; ++i)
        #pragma unroll
        for (int j = 0; j < 4; ++j)
          acc[i][j] = __builtin_amdgcn_mfma_f32_16x16x32_f16(af[i], bf[j], acc[i][j], 0, 0, 0);
    }
  }

  float zacc[4][4];
  #pragma unroll
  for (int i = 0; i < 4; ++i)
    #pragma unroll
    for (int r = 0; r < 4; ++r) zacc[i][r] = 0.0f;

  #pragma unroll
  for (int i = 0; i < 4; ++i) {
    #pragma unroll
    for (int j = 0; j < 4; ++j) {
      const int inCol = wc * 64 + j * 16 + l15;
      const int gcol  = s0 + inCol;
      #pragma unroll
      for (int r = 0; r < 4; ++r) {
        const int rowL = wr * 64 + i * 16 + quad * 4 + r;
        float sV = acc[i][j][r] * COEF;
        sV = fminf(fmaxf(sV, -60.f), 60.f);
        const float e = (gcol <= t0 + rowL) ? __expf(sV) : 0.f;
        const float pe = __shfl_xor(e, 1);
        if ((lane & 1) == 0) {
          const uint pk = (uint)bf16_bits(e) | ((uint)bf16_bits(pe) << 16);
          *(uint*)&EhT[rowL * 128 + inCol] = pk;
        }
        zacc[i][r] += e;
      }
    }
  }
  #pragma unroll
  for (int i = 0; i < 4; ++i)
    #pragma unroll
    for (int r = 0; r < 4; ++r) {
      float v = zacc[i][r];
      v += __shfl_xor(v, 1);
      v += __shfl_xor(v, 2);
      v += __shfl_xor(v, 4);
      v += __shfl_xor(v, 8);
      if (l15 == 0)
        atomicAdd(&zbuf[b * Tn + t0 + wr * 64 + i * 16 + quad * 4 + r], v);
    }
}

// In-place W-build: E[t,s] *= (sv[t] + sv[s] - 2), packed single-bf16 tiles.
// sv computed inline from raw zbuf + aab (R8). 1D grid 544, XCD-aligned
// decode (R10).
__global__ void __launch_bounds__(256) wbuild_kernel(
    ushort* __restrict__ Ehp, const float* __restrict__ zbuf,
    const float* __restrict__ aab, const float* __restrict__ cst, int ps_idx) {
  int b, it, st;
  etile_decode(blockIdx.x, b, it, st);
  const int tri = it * (it + 1) / 2 + st;
  ushort* EhT = Ehp + ((size_t)b * NTRI + tri) * 16384;
  const float ps = cst[ps_idx];
  const float ps2 = ps * ps;

  const int tid = threadIdx.x;
  __shared__ float scol[128];
  if (tid < 128) {
    const int i = b * Tn + st * 128 + tid;
    scol[tid] = sv_of(zbuf[i], aab[i], ps2);
  }
  __syncthreads();

  const int r  = tid >> 1;            // 0..127
  const int ch = (tid & 1) * 64;      // col half
  const int irow = b * Tn + it * 128 + r;
  const float svt2 = sv_of(zbuf[irow], aab[irow], ps2) - 2.0f;
  const int base = r * 128 + ch;
  #pragma unroll
  for (int v = 0; v < 8; ++v) {
    u16x8 h8 = *(const u16x8*)&EhT[base + v * 8];
    u16x8 nh;
    #pragma unroll
    for (int q = 0; q < 8; ++q) {
      const float w = bits_to_f(h8[q]) * (svt2 + scol[ch + v * 8 + q]);
      nh[q] = bf16_bits(w);
    }
    *(u16x8*)&EhT[base + v * 8] = nh;
  }
}

// core GEMM + fused elementwise epilogues. K=64 double-slab chunks, R0
// 2-barrier loop, 128t x 64c tile, grid 768. R7 XCD-paired balanced
// swizzle. z finalization inline (R8) — zb holds RAW row sums.
template <int MODE>
__global__ void __launch_bounds__(256) corepass_mfma(
    const ushort* __restrict__ Whp, const ushort* __restrict__ XT,
    const float* src, float* dst,
    const float* __restrict__ cst, int ss_idx, int lam_idx,
    float* eA, float* eB, float* eC, float* eD,
    const float* __restrict__ zb, int vel_idx, float rc, float rs) {
  const int id = blockIdx.x;
  const int x  = id & 7;                 // XCD class
  const int n  = id >> 3;                // 0..95
  const int k  = n / 12;                 // strip 0..7 within class
  const int ic = n - k * 12;             // 0..11
  const int b  = k & 3;
  const int it = (k >> 2) ? x : (15 - x);   // big strips first
  const int t0 = it * 128, c0 = ic * 64;

  const int tid  = threadIdx.x;
  const int lane = tid & 63;
  const int wv   = tid >> 6;
  const int wr   = wv >> 1, wc = wv & 1;   // wave covers 64t x 32c
  const int quad = lane >> 4, l15 = lane & 15;

  const ushort* WhB = Whp + (size_t)b * NTRI * 16384;
  const ushort* XTb = XT + (size_t)b * Cn * Tn;

  __shared__ ushort Ah[2][128 * 32];   // W slabs  (16 KB)
  __shared__ ushort Bh[2][64 * 32];    // X^T slabs (8 KB)

  const int srow = lane >> 2;
  const int scol = (lane & 3) * 8;
  const int triBase = it * (it + 1) / 2;

  f32x4 acc[4][2] = {};
  const int chunks = (it + 1) * 2;           // 64-k chunks
  for (int kc = 0; kc < chunks; ++kc) {
    const int ss0 = kc * 64;
    const int stile = kc >> 1, soff = (kc & 1) * 64;
    const ushort* tileB = WhB + (size_t)(triBase + stile) * 16384 + soff;

    __syncthreads();                 // prev chunk's LDS reads done
    #pragma unroll
    for (int h = 0; h < 2; ++h) {
      const ushort* tileH = tileB + h * 32;
      const int rb0 = wv * 16, rb1 = 64 + wv * 16;
      gload16(tileH + (size_t)(rb0 + srow) * 128 + scol, Ah[h] + rb0 * 32);
      gload16(tileH + (size_t)(rb1 + srow) * 128 + scol, Ah[h] + rb1 * 32);
      gload16(XTb + (size_t)(c0 + wv * 16 + srow) * Tn + ss0 + h * 32 + scol,
              Bh[h] + wv * 16 * 32);
    }
    __syncthreads();                 // drain vmcnt

    #pragma unroll
    for (int h = 0; h < 2; ++h) {
      bf16x8 ah[4], bh[2];
      #pragma unroll
      for (int i = 0; i < 4; ++i)
        ah[i] = *(const bf16x8*)&Ah[h][(wr * 64 + i * 16 + l15) * 32 + quad * 8];
      #pragma unroll
      for (int j = 0; j < 2; ++j)
        bh[j] = *(const bf16x8*)&Bh[h][(wc * 32 + j * 16 + l15) * 32 + quad * 8];
      #pragma unroll
      for (int i = 0; i < 4; ++i)
        #pragma unroll
        for (int j = 0; j < 2; ++j)
          acc[i][j] = __builtin_amdgcn_mfma_f32_16x16x32_bf16(ah[i], bh[j], acc[i][j], 0, 0, 0);
    }
  }

  const float coef = 0.5f * cst[lam_idx] * (1.0f / (2.0f * Tn));
  const float ssc = cst[ss_idx];
  const float vs = 0.5f * cst[vel_idx];
  #pragma unroll
  for (int i = 0; i < 4; ++i) {
    #pragma unroll
    for (int j = 0; j < 2; ++j) {
      const int col = c0 + wc * 32 + j * 16 + l15;
      #pragma unroll
      for (int r = 0; r < 4; ++r) {
        const int row = t0 + wr * 64 + i * 16 + quad * 4 + r;
        const size_t off = ((size_t)b * Tn + row) * Cn + col;
        const float srcv = src[off];
        const float d = srcv * ssc + coef * acc[i][j][r];
        if (MODE == 0) {
          const float z = fmaxf(zb[b * Tn + row] * (1.0f / Tn), EPSZ);
          dst[off] = d;
          eC[off] = eA[off] + vs * srcv / z;
        } else if (MODE == 1) {
          const float z = fmaxf(zb[b * Tn + row] * (1.0f / Tn), EPSZ);
          const float po = eB[off];
          const float xo = eA[off] + vs * po / z;
          const float bx = eC[off];
          const float dX = xo - bx, dPi = po - d;
          const float sX = xo + bx, sPi = po + d;
          eD[off]  = 0.5f * (sX + rc * dX + rs * dPi);   // Xo
          eB[off]  = 0.5f * (sPi - rs * dX + rc * dPi);  // Po
          eC[off]  = 0.5f * (sX - rc * dX - rs * dPi);   // bX
          dst[off] = 0.5f * (sPi + rs * dX - rc * dPi);  // bPi
        } else if (MODE == 2) {
          const float z = fmaxf(zb[b * Tn + row] * (1.0f / Tn), EPSZ);
          dst[off] = d;
          eA[off] = eA[off] + vs * eB[off] / z;
        } else {
          dst[off] = d;
        }
      }
    }
  }
}

// Wave-per-row final LayerNorm (fp32 out, in-place capable) (R11).
__global__ void __launch_bounds__(256) ln_f32_kernel(
    const float* src, const float* __restrict__ w,
    float* dst, const float* __restrict__ cst, int alpha_idx) {
  const int lane = threadIdx.x & 63;
  const int row  = blockIdx.x * 4 + (threadIdx.x >> 6);
  const float alpha = cst[alpha_idx];
  const float* x = src + (size_t)row * Cn;

  float4 v[3];
  float s = 0.f;
  #pragma unroll
  for (int q = 0; q < 3; ++q) {
    v[q] = *(const float4*)&x[q * 256 + lane * 4];
    v[q].x *= alpha; v[q].y *= alpha; v[q].z *= alpha; v[q].w *= alpha;
    s += v[q].x + v[q].y + v[q].z + v[q].w;
  }
  s = wave_sum(s);
  const float m = s * (1.0f / Cn);
  float vs = 0.f;
  #pragma unroll
  for (int q = 0; q < 3; ++q) {
    v[q].x -= m; v[q].y -= m; v[q].z -= m; v[q].w -= m;
    vs += v[q].x * v[q].x + v[q].y * v[q].y + v[q].z * v[q].z + v[q].w * v[q].w;
  }
  vs = wave_sum(vs);
  const float rstd = rsqrtf(vs * (1.0f / Cn) + LNEPS);

  float* y = dst + (size_t)row * Cn;
  #pragma unroll
  for (int q = 0; q < 3; ++q) {
    const float4 w4 = *(const float4*)&w[q * 256 + lane * 4];
    float4 o;
    o.x = v[q].x * rstd * w4.x;
    o.y = v[q].y * rstd * w4.y;
    o.z = v[q].z * rstd * w4.z;
    o.w = v[q].w * rstd * w4.w;
    *(float4*)&y[q * 256 + lane * 4] = o;
  }
}

extern "C" void kernel_launch(void* const* d_in, const int* in_sizes, int n_in,
                              void* d_out, int out_size, void* d_ws, size_t ws_size,
                              hipStream_t stream) {
  (void)in_sizes; (void)n_in; (void)out_size;
  const float* Xk  = (const float*)d_in[0];
  const float* Pk  = (const float*)d_in[1];
  const float* lw  = (const float*)d_in[2];
  const float* lvw = (const float*)d_in[3];
  const int*   kp  = (const int*)d_in[4];

  float* Xo = (float*)d_out;        // X state in d_out[0:BTC]
  float* Po = Xo + NBTC;            // Pi state in d_out[BTC:2BTC]

  char* wp = (char*)d_ws;
  float*  bX  = (float*)wp;  wp += NBTC * sizeof(float);
  float*  bPi = (float*)wp;  wp += NBTC * sizeof(float);
  f16_t*  XnF = (f16_t*)wp;  wp += NBTC * sizeof(f16_t);
  ushort* Ehp = (ushort*)wp; wp += (size_t)Bn * NTRI * 16384 * sizeof(ushort);
  ushort* XTh = (ushort*)wp; wp += NBTC * sizeof(ushort);
  float*  zb  = (float*)wp;  wp += (size_t)Bn * Tn * sizeof(float);
  float*  aab = (float*)wp;  wp += (size_t)Bn * Tn * sizeof(float);
  float*  cst = (float*)wp;  wp += 256;
  const size_t need = (size_t)(wp - (char*)d_ws);
  if (ws_size < need) {
    fprintf(stderr, "[kernel] ws too small: %zu < %zu\n", ws_size, need);
    return;
  }

  const dim3 b256(256);
  const dim3 gLN(Bn * Tn / 4);               // wave-per-row, 4 rows/block
  const dim3 gXT(Tn / 64, Cn / 64, Bn);      // (32,12,4)
  const dim3 gZ(544);                        // XCD-aligned E-tile decode
  const dim3 gW(544);                        // same decode (no dead blocks)
  const dim3 gCore(768);                     // XCD-paired balanced swizzle
  const float rc = (float)cos(2.0), rs = (float)sin(2.0);   // theta = 2*XI*h

  prep_consts<<<1, 1, 0, stream>>>(kp, cst);

  // ---- Stage A: X-side = Xk, p = Pk (lam*Lam = 1) ----
  ln_sv_kernel<<<gLN, b256, 0, stream>>>(Xk, lw, XnF, zb, aab, Pk, cst, 6);
  xt_kernel<<<gXT, b256, 0, stream>>>((const ushort*)XnF, XTh);
  zpass_mfma<<<gZ, b256, 0, stream>>>(XnF, Ehp, zb);
  wbuild_kernel<<<gW, b256, 0, stream>>>(Ehp, zb, aab, cst, 6);
  corepass_mfma<0><<<gCore, b256, 0, stream>>>(Ehp, XTh, Pk, Po, cst, 0, 0,
      (float*)Xk, nullptr, bX, nullptr, zb, 6, rc, rs);

  // ---- Stage B: X-side = bX, Pi-side = Po; fused velupd-B + rotation ----
  ln_sv_kernel<<<gLN, b256, 0, stream>>>(bX, lw, XnF, zb, aab, Po, cst, 6);
  xt_kernel<<<gXT, b256, 0, stream>>>((const ushort*)XnF, XTh);
  zpass_mfma<<<gZ, b256, 0, stream>>>(XnF, Ehp, zb);
  wbuild_kernel<<<gW, b256, 0, stream>>>(Ehp, zb, aab, cst, 3);
  corepass_mfma<1><<<gCore, b256, 0, stream>>>(Ehp, XTh, Pk, bPi, cst, 0, 2,
      (float*)Xk, Po, bX, Xo, zb, 3, rc, rs);

  // ---- Stage C: X-side = bX, Pi-side = Po; fused velupd-C ----
  ln_sv_kernel<<<gLN, b256, 0, stream>>>(bX, lw, XnF, zb, aab, Po, cst, 6);
  xt_kernel<<<gXT, b256, 0, stream>>>((const ushort*)XnF, XTh);
  zpass_mfma<<<gZ, b256, 0, stream>>>(XnF, Ehp, zb);
  wbuild_kernel<<<gW, b256, 0, stream>>>(Ehp, zb, aab, cst, 3);
  corepass_mfma<2><<<gCore, b256, 0, stream>>>(Ehp, XTh, bPi, bPi, cst, 6, 2,
      Xo, Po, nullptr, nullptr, zb, 3, rc, rs);

  // ---- Stage D: X-side = Xo, p = lam_tk1*bPi ----
  ln_sv_kernel<<<gLN, b256, 0, stream>>>(Xo, lw, XnF, zb, aab, bPi, cst, 6);
  xt_kernel<<<gXT, b256, 0, stream>>>((const ushort*)XnF, XTh);
  zpass_mfma<<<gZ, b256, 0, stream>>>(XnF, Ehp, zb);
  wbuild_kernel<<<gW, b256, 0, stream>>>(Ehp, zb, aab, cst, 5);
  corepass_mfma<3><<<gCore, b256, 0, stream>>>(Ehp, XTh, Po, Po, cst, 6, 4,
      nullptr, nullptr, nullptr, nullptr, zb, 6, rc, rs);

  // ---- Final: Pk1 = LN(lam_tk1 * Pi) * ln_v_w (in place on Po) ----
  ln_f32_kernel<<<gLN, b256, 0, stream>>>(Po, lvw, Po, cst, 5);
}

// Round 14
// 521.006 us; speedup vs baseline: 1.1250x; 1.0371x over previous
//
#include <hip/hip_runtime.h>
#include <hip/hip_bf16.h>
#include <cstdio>
#include <cmath>

// Problem constants (B,T,C,NH fixed by the reference)
constexpr int   Bn = 4;
constexpr int   Tn = 2048;
constexpr int   Cn = 768;
constexpr float COEF  = 0.125f / 12.0f;   // SCALE / NH
constexpr float EPSZ  = 1e-8f;
constexpr float LNEPS = 1e-5f;
constexpr int   NTRI  = 136;              // triangular 128-tiles per batch
#define NBTC ((size_t)Bn * Tn * Cn)

typedef __bf16 bf16_t;
typedef _Float16 f16_t;
typedef bf16_t bf16x8 __attribute__((ext_vector_type(8)));
typedef f16_t  f16x8  __attribute__((ext_vector_type(8)));
typedef f16_t  f16x4  __attribute__((ext_vector_type(4)));
typedef float  f32x4  __attribute__((ext_vector_type(4)));
typedef ushort u16x8  __attribute__((ext_vector_type(8)));

// async global->LDS, 16B per lane. LDS dest is wave-uniform base + lane*16.
__device__ __forceinline__ void gload16(const void* g, void* l) {
  __builtin_amdgcn_global_load_lds(
      (const __attribute__((address_space(1))) unsigned int*)g,
      (__attribute__((address_space(3))) unsigned int*)l,
      16, 0, 0);
}

__device__ __forceinline__ ushort bf16_bits(float f) {
  bf16_t h = (bf16_t)f;
  return __builtin_bit_cast(ushort, h);
}
__device__ __forceinline__ float bits_to_f(ushort u) {
  return (float)__builtin_bit_cast(bf16_t, u);
}
__device__ __forceinline__ ushort f16bits_to_bf16bits(ushort u) {
  const float f = (float)__builtin_bit_cast(f16_t, u);
  return bf16_bits(f);
}

__device__ __forceinline__ float4 ld4f(const float* p) { return *(const float4*)p; }
__device__ __forceinline__ float4 ld4bf(const ushort* p) {
  const ushort4 u = *(const ushort4*)p;
  float4 r;
  r.x = bits_to_f(u.x); r.y = bits_to_f(u.y);
  r.z = bits_to_f(u.z); r.w = bits_to_f(u.w);
  return r;
}

__device__ __forceinline__ float wave_sum(float v) {
  #pragma unroll
  for (int off = 32; off > 0; off >>= 1) v += __shfl_xor(v, off);
  return v;
}

// sv from raw zpass row-sum: zf = max(sum/Tn, EPSZ); sv = a*ps^2/(zf^2+EPSZ)
__device__ __forceinline__ float sv_of(float zraw, float a, float ps2) {
  const float zf = fmaxf(zraw * (1.0f / Tn), EPSZ);
  return a * ps2 / (zf * zf + EPSZ);
}

// E-tile XCD-aligned decode (R10): id in [0,544): x=id&7, m=id>>3, b=m/17,
// u=m%17; u<=x: (it,jm)=(x,u) else (15-x, u-x-1). Equal work per class.
__device__ __forceinline__ void etile_decode(int id, int& b, int& it, int& jm) {
  const int x = id & 7;
  const int m = id >> 3;
  b = m / 17;
  const int u = m - b * 17;
  if (u <= x) { it = x;      jm = u; }
  else        { it = 15 - x; jm = u - x - 1; }
}

// cst[] indices: 0 Lam_tk, 1 lam_tk, 2 Lam_tbar, 3 lam_tbar, 4 Lam_tk1, 5 lam_tk1, 6 = 1.0
__global__ void prep_consts(const int* kp, float* cst) {
  if (threadIdx.x == 0 && blockIdx.x == 0) {
    float tk = 1.0f + (float)(*kp);
    float tb = tk + 0.5f;
    float t1 = tk + 1.0f;
    cst[0] = tk * tk * tk; cst[1] = 1.0f / cst[0];
    cst[2] = tb * tb * tb; cst[3] = 1.0f / cst[2];
    cst[4] = t1 * t1 * t1; cst[5] = 1.0f / cst[4];
    cst[6] = 1.0f;
  }
}

// Wave-per-row LayerNorm (R11), fp16-only output (R13). R14: templated on
// src/Pi dtype — bX and bPi intermediate states are now bf16 in HBM.
// LayerNorm of (alpha*src) -> fp16, PLUS |Pi row|^2 -> aab. Also zeroes
// zbuf[row] for zpass atomics. 4 rows/block, grid 2048.
template <bool SRC_BF, bool PI_BF>
__global__ void __launch_bounds__(256) ln_sv_kernel(
    const void* __restrict__ srcv_, const float* __restrict__ w,
    f16_t* __restrict__ outF,
    float* __restrict__ zbuf, float* __restrict__ aab,
    const void* __restrict__ Pisrc_,
    const float* __restrict__ cst, int alpha_idx) {
  const int lane = threadIdx.x & 63;
  const int row  = blockIdx.x * 4 + (threadIdx.x >> 6);
  const float alpha = cst[alpha_idx];
  const size_t base = (size_t)row * Cn;

  float4 v[3];
  float s = 0.f;
  #pragma unroll
  for (int q = 0; q < 3; ++q) {
    if (SRC_BF)
      v[q] = ld4bf((const ushort*)srcv_ + base + q * 256 + lane * 4);
    else
      v[q] = ld4f((const float*)srcv_ + base + q * 256 + lane * 4);
    v[q].x *= alpha; v[q].y *= alpha; v[q].z *= alpha; v[q].w *= alpha;
    s += v[q].x + v[q].y + v[q].z + v[q].w;
  }
  s = wave_sum(s);
  const float m = s * (1.0f / Cn);
  float vs = 0.f;
  #pragma unroll
  for (int q = 0; q < 3; ++q) {
    v[q].x -= m; v[q].y -= m; v[q].z -= m; v[q].w -= m;
    vs += v[q].x * v[q].x + v[q].y * v[q].y + v[q].z * v[q].z + v[q].w * v[q].w;
  }
  vs = wave_sum(vs);
  const float rstd = rsqrtf(vs * (1.0f / Cn) + LNEPS);

  #pragma unroll
  for (int q = 0; q < 3; ++q) {
    const float4 w4 = *(const float4*)&w[q * 256 + lane * 4];
    const float f0 = v[q].x * rstd * w4.x;
    const float f1 = v[q].y * rstd * w4.y;
    const float f2 = v[q].z * rstd * w4.z;
    const float f3 = v[q].w * rstd * w4.w;
    f16x4 hf = {(f16_t)f0, (f16_t)f1, (f16_t)f2, (f16_t)f3};
    *(f16x4*)&outF[base + q * 256 + lane * 4] = hf;
  }

  // |p|^2 reduction of the Pi-side row
  float a = 0.f;
  #pragma unroll
  for (int q = 0; q < 3; ++q) {
    float4 p4;
    if (PI_BF)
      p4 = ld4bf((const ushort*)Pisrc_ + base + q * 256 + lane * 4);
    else
      p4 = ld4f((const float*)Pisrc_ + base + q * 256 + lane * 4);
    a += p4.x * p4.x + p4.y * p4.y + p4.z * p4.z + p4.w * p4.w;
  }
  a = wave_sum(a);
  if (lane == 0) {
    aab[row] = a;
    zbuf[row] = 0.0f;
  }
}

// Transpose XnF(fp16) [b][s][c] -> XT [b][c][s] (bf16), converting
// fp16->bf16 on the load side (Xnb buffer eliminated).
// grid (Tn/64, Cn/64, Bn).
__global__ void __launch_bounds__(256) xt_kernel(
    const ushort* __restrict__ XhF, ushort* __restrict__ XT) {
  const int b = blockIdx.z;
  const int s0 = blockIdx.x * 64, c0 = blockIdx.y * 64;
  const int tid = threadIdx.x;
  __shared__ ushort t[64][68];
  const ushort* src = XhF + (size_t)b * Tn * Cn;
  ushort* dst = XT + (size_t)b * Cn * Tn;
  #pragma unroll
  for (int p = 0; p < 4; ++p) {
    const int r = p * 16 + (tid >> 4);
    const int c = (tid & 15) * 4;
    const ushort4 v = *(const ushort4*)&src[(size_t)(s0 + r) * Cn + c0 + c];
    ushort4 bv;
    bv.x = f16bits_to_bf16bits(v.x);
    bv.y = f16bits_to_bf16bits(v.y);
    bv.z = f16bits_to_bf16bits(v.z);
    bv.w = f16bits_to_bf16bits(v.w);
    *(ushort4*)&t[r][c] = bv;
  }
  __syncthreads();
  #pragma unroll
  for (int p = 0; p < 4; ++p) {
    const int cc = p * 16 + (tid >> 4);
    const int ss = (tid & 15) * 4;
    ushort4 o;
    o.x = t[ss + 0][cc]; o.y = t[ss + 1][cc];
    o.z = t[ss + 2][cc]; o.w = t[ss + 3][cc];
    *(ushort4*)&dst[(size_t)(c0 + cc) * Tn + s0 + ss] = o;
  }
}

// Causal gram, 128x128 tiles (R9), BK=64 / 32 KB LDS (R13), XCD-aligned
// 1D grid 544 (R10). E = exp(clip(S*COEF)) stored single-bf16 pair-packed.
// Row sums -> atomicAdd zbuf. block 256, acc[4][4].
__global__ void __launch_bounds__(256) zpass_mfma(
    const f16_t* __restrict__ XnF,
    ushort* __restrict__ Ehp, float* __restrict__ zbuf) {
  int b, it, jm;
  etile_decode(blockIdx.x, b, it, jm);
  const int l = it * (it + 1) / 2 + jm;
  const int t0 = it * 128, s0 = jm * 128;

  const int tid  = threadIdx.x;
  const int lane = tid & 63;
  const int wv   = tid >> 6;
  const int wr   = wv >> 1, wc = wv & 1;     // wave covers 64t x 64s
  const int quad = lane >> 4, l15 = lane & 15;

  const f16_t* XbF = XnF + (size_t)b * Tn * Cn;
  ushort* EhT = Ehp + ((size_t)b * NTRI + l) * 16384;

  __shared__ f16_t Af[2][128 * 32];   // 16 KB
  __shared__ f16_t Bf[2][128 * 32];   // 16 KB

  const int srow = lane >> 2;                // 0..15
  const int scol = (lane & 3) * 8;

  f32x4 acc[4][4] = {};

  for (int c0 = 0; c0 < Cn; c0 += 64) {
    __syncthreads();                 // protect LDS while prev chunk still read
    #pragma unroll
    for (int h = 0; h < 2; ++h) {
      const int cb = c0 + h * 32;
      const int rb0 = wv * 16, rb1 = 64 + wv * 16;
      gload16(XbF + (size_t)(t0 + rb0 + srow) * Cn + cb + scol, Af[h] + rb0 * 32);
      gload16(XbF + (size_t)(t0 + rb1 + srow) * Cn + cb + scol, Af[h] + rb1 * 32);
      gload16(XbF + (size_t)(s0 + rb0 + srow) * Cn + cb + scol, Bf[h] + rb0 * 32);
      gload16(XbF + (size_t)(s0 + rb1 + srow) * Cn + cb + scol, Bf[h] + rb1 * 32);
    }
    __syncthreads();                 // drain vmcnt + all slabs present

    #pragma unroll
    for (int h = 0; h < 2; ++h) {
      f16x8 af[4], bf[4];
      #pragma unroll
      for (int i = 0; i < 4; ++i)
        af[i] = *(const f16x8*)&Af[h][(wr * 64 + i * 16 + l15) * 32 + quad * 8];
      #pragma unroll
      for (int j = 0; j < 4; ++j)
        bf[j] = *(const f16x8*)&Bf[h][(wc * 64 + j * 16 + l15) * 32 + quad * 8];
      #pragma unroll
      for (int i = 0; i < 4; ++i)
        #pragma unroll
        for (int j = 0; j < 4; ++j)
          acc[i][j] = __builtin_amdgcn_mfma_f32_16x16x32_f16(af[i], bf[j], acc[i][j], 0, 0, 0);
    }
  }

  float zacc[4][4];
  #pragma unroll
  for (int i = 0; i < 4; ++i)
    #pragma unroll
    for (int r = 0; r < 4; ++r) zacc[i][r] = 0.0f;

  #pragma unroll
  for (int i = 0; i < 4; ++i) {
    #pragma unroll
    for (int j = 0; j < 4; ++j) {
      const int inCol = wc * 64 + j * 16 + l15;
      const int gcol  = s0 + inCol;
      #pragma unroll
      for (int r = 0; r < 4; ++r) {
        const int rowL = wr * 64 + i * 16 + quad * 4 + r;
        float sV = acc[i][j][r] * COEF;
        sV = fminf(fmaxf(sV, -60.f), 60.f);
        const float e = (gcol <= t0 + rowL) ? __expf(sV) : 0.f;
        const float pe = __shfl_xor(e, 1);
        if ((lane & 1) == 0) {
          const uint pk = (uint)bf16_bits(e) | ((uint)bf16_bits(pe) << 16);
          *(uint*)&EhT[rowL * 128 + inCol] = pk;
        }
        zacc[i][r] += e;
      }
    }
  }
  #pragma unroll
  for (int i = 0; i < 4; ++i)
    #pragma unroll
    for (int r = 0; r < 4; ++r) {
      float v = zacc[i][r];
      v += __shfl_xor(v, 1);
      v += __shfl_xor(v, 2);
      v += __shfl_xor(v, 4);
      v += __shfl_xor(v, 8);
      if (l15 == 0)
        atomicAdd(&zbuf[b * Tn + t0 + wr * 64 + i * 16 + quad * 4 + r], v);
    }
}

// In-place W-build: E[t,s] *= (sv[t] + sv[s] - 2), packed single-bf16 tiles.
// sv computed inline from raw zbuf + aab (R8). 1D grid 544, XCD-aligned
// decode (R10).
__global__ void __launch_bounds__(256) wbuild_kernel(
    ushort* __restrict__ Ehp, const float* __restrict__ zbuf,
    const float* __restrict__ aab, const float* __restrict__ cst, int ps_idx) {
  int b, it, st;
  etile_decode(blockIdx.x, b, it, st);
  const int tri = it * (it + 1) / 2 + st;
  ushort* EhT = Ehp + ((size_t)b * NTRI + tri) * 16384;
  const float ps = cst[ps_idx];
  const float ps2 = ps * ps;

  const int tid = threadIdx.x;
  __shared__ float scol[128];
  if (tid < 128) {
    const int i = b * Tn + st * 128 + tid;
    scol[tid] = sv_of(zbuf[i], aab[i], ps2);
  }
  __syncthreads();

  const int r  = tid >> 1;            // 0..127
  const int ch = (tid & 1) * 64;      // col half
  const int irow = b * Tn + it * 128 + r;
  const float svt2 = sv_of(zbuf[irow], aab[irow], ps2) - 2.0f;
  const int base = r * 128 + ch;
  #pragma unroll
  for (int v = 0; v < 8; ++v) {
    u16x8 h8 = *(const u16x8*)&EhT[base + v * 8];
    u16x8 nh;
    #pragma unroll
    for (int q = 0; q < 8; ++q) {
      const float w = bits_to_f(h8[q]) * (svt2 + scol[ch + v * 8 + q]);
      nh[q] = bf16_bits(w);
    }
    *(u16x8*)&EhT[base + v * 8] = nh;
  }
}

// core GEMM + fused elementwise epilogues. K=64 double-slab chunks, R0
// 2-barrier loop, 128t x 64c tile, grid 768. R7 XCD-paired balanced
// swizzle. z finalization inline (R8) — zb holds RAW row sums.
// R14: bX (eC) and bPi (dst in MODE1/2, src in MODE2) are bf16 in HBM.
template <int MODE>
__global__ void __launch_bounds__(256) corepass_mfma(
    const ushort* __restrict__ Whp, const ushort* __restrict__ XT,
    const float* src, float* dst,
    const float* __restrict__ cst, int ss_idx, int lam_idx,
    float* eA, float* eB, float* eC, float* eD,
    const float* __restrict__ zb, int vel_idx, float rc, float rs) {
  const int id = blockIdx.x;
  const int x  = id & 7;                 // XCD class
  const int n  = id >> 3;                // 0..95
  const int k  = n / 12;                 // strip 0..7 within class
  const int ic = n - k * 12;             // 0..11
  const int b  = k & 3;
  const int it = (k >> 2) ? x : (15 - x);   // big strips first
  const int t0 = it * 128, c0 = ic * 64;

  const int tid  = threadIdx.x;
  const int lane = tid & 63;
  const int wv   = tid >> 6;
  const int wr   = wv >> 1, wc = wv & 1;   // wave covers 64t x 32c
  const int quad = lane >> 4, l15 = lane & 15;

  const ushort* WhB = Whp + (size_t)b * NTRI * 16384;
  const ushort* XTb = XT + (size_t)b * Cn * Tn;

  __shared__ ushort Ah[2][128 * 32];   // W slabs  (16 KB)
  __shared__ ushort Bh[2][64 * 32];    // X^T slabs (8 KB)

  const int srow = lane >> 2;
  const int scol = (lane & 3) * 8;
  const int triBase = it * (it + 1) / 2;

  f32x4 acc[4][2] = {};
  const int chunks = (it + 1) * 2;           // 64-k chunks
  for (int kc = 0; kc < chunks; ++kc) {
    const int ss0 = kc * 64;
    const int stile = kc >> 1, soff = (kc & 1) * 64;
    const ushort* tileB = WhB + (size_t)(triBase + stile) * 16384 + soff;

    __syncthreads();                 // prev chunk's LDS reads done
    #pragma unroll
    for (int h = 0; h < 2; ++h) {
      const ushort* tileH = tileB + h * 32;
      const int rb0 = wv * 16, rb1 = 64 + wv * 16;
      gload16(tileH + (size_t)(rb0 + srow) * 128 + scol, Ah[h] + rb0 * 32);
      gload16(tileH + (size_t)(rb1 + srow) * 128 + scol, Ah[h] + rb1 * 32);
      gload16(XTb + (size_t)(c0 + wv * 16 + srow) * Tn + ss0 + h * 32 + scol,
              Bh[h] + wv * 16 * 32);
    }
    __syncthreads();                 // drain vmcnt

    #pragma unroll
    for (int h = 0; h < 2; ++h) {
      bf16x8 ah[4], bh[2];
      #pragma unroll
      for (int i = 0; i < 4; ++i)
        ah[i] = *(const bf16x8*)&Ah[h][(wr * 64 + i * 16 + l15) * 32 + quad * 8];
      #pragma unroll
      for (int j = 0; j < 2; ++j)
        bh[j] = *(const bf16x8*)&Bh[h][(wc * 32 + j * 16 + l15) * 32 + quad * 8];
      #pragma unroll
      for (int i = 0; i < 4; ++i)
        #pragma unroll
        for (int j = 0; j < 2; ++j)
          acc[i][j] = __builtin_amdgcn_mfma_f32_16x16x32_bf16(ah[i], bh[j], acc[i][j], 0, 0, 0);
    }
  }

  const float coef = 0.5f * cst[lam_idx] * (1.0f / (2.0f * Tn));
  const float ssc = cst[ss_idx];
  const float vs = 0.5f * cst[vel_idx];
  #pragma unroll
  for (int i = 0; i < 4; ++i) {
    #pragma unroll
    for (int j = 0; j < 2; ++j) {
      const int col = c0 + wc * 32 + j * 16 + l15;
      #pragma unroll
      for (int r = 0; r < 4; ++r) {
        const int row = t0 + wr * 64 + i * 16 + quad * 4 + r;
        const size_t off = ((size_t)b * Tn + row) * Cn + col;
        // src: bf16 (bPi) in MODE2, fp32 elsewhere
        const float srcv = (MODE == 2) ? bits_to_f(((const ushort*)src)[off])
                                       : src[off];
        const float d = srcv * ssc + coef * acc[i][j][r];
        if (MODE == 0) {
          const float z = fmaxf(zb[b * Tn + row] * (1.0f / Tn), EPSZ);
          dst[off] = d;                                   // Po (f32)
          ((ushort*)eC)[off] = bf16_bits(eA[off] + vs * srcv / z);  // bX (bf16)
        } else if (MODE == 1) {
          const float z = fmaxf(zb[b * Tn + row] * (1.0f / Tn), EPSZ);
          const float po = eB[off];
          const float xo = eA[off] + vs * po / z;
          const float bx = bits_to_f(((const ushort*)eC)[off]);     // bX (bf16)
          const float dX = xo - bx, dPi = po - d;
          const float sX = xo + bx, sPi = po + d;
          eD[off] = 0.5f * (sX + rc * dX + rs * dPi);               // Xo (f32)
          eB[off] = 0.5f * (sPi - rs * dX + rc * dPi);              // Po (f32)
          ((ushort*)eC)[off] = bf16_bits(0.5f * (sX - rc * dX - rs * dPi)); // bX
          ((ushort*)dst)[off] = bf16_bits(0.5f * (sPi + rs * dX - rc * dPi)); // bPi
        } else if (MODE == 2) {
          const float z = fmaxf(zb[b * Tn + row] * (1.0f / Tn), EPSZ);
          ((ushort*)dst)[off] = bf16_bits(d);             // bPi (bf16)
          eA[off] = eA[off] + vs * eB[off] / z;           // Xo (f32)
        } else {
          dst[off] = d;                                   // Po (f32)
        }
      }
    }
  }
}

// Wave-per-row final LayerNorm (fp32 out, in-place capable) (R11).
__global__ void __launch_bounds__(256) ln_f32_kernel(
    const float* src, const float* __restrict__ w,
    float* dst, const float* __restrict__ cst, int alpha_idx) {
  const int lane = threadIdx.x & 63;
  const int row  = blockIdx.x * 4 + (threadIdx.x >> 6);
  const float alpha = cst[alpha_idx];
  const float* x = src + (size_t)row * Cn;

  float4 v[3];
  float s = 0.f;
  #pragma unroll
  for (int q = 0; q < 3; ++q) {
    v[q] = *(const float4*)&x[q * 256 + lane * 4];
    v[q].x *= alpha; v[q].y *= alpha; v[q].z *= alpha; v[q].w *= alpha;
    s += v[q].x + v[q].y + v[q].z + v[q].w;
  }
  s = wave_sum(s);
  const float m = s * (1.0f / Cn);
  float vs = 0.f;
  #pragma unroll
  for (int q = 0; q < 3; ++q) {
    v[q].x -= m; v[q].y -= m; v[q].z -= m; v[q].w -= m;
    vs += v[q].x * v[q].x + v[q].y * v[q].y + v[q].z * v[q].z + v[q].w * v[q].w;
  }
  vs = wave_sum(vs);
  const float rstd = rsqrtf(vs * (1.0f / Cn) + LNEPS);

  float* y = dst + (size_t)row * Cn;
  #pragma unroll
  for (int q = 0; q < 3; ++q) {
    const float4 w4 = *(const float4*)&w[q * 256 + lane * 4];
    float4 o;
    o.x = v[q].x * rstd * w4.x;
    o.y = v[q].y * rstd * w4.y;
    o.z = v[q].z * rstd * w4.z;
    o.w = v[q].w * rstd * w4.w;
    *(float4*)&y[q * 256 + lane * 4] = o;
  }
}

extern "C" void kernel_launch(void* const* d_in, const int* in_sizes, int n_in,
                              void* d_out, int out_size, void* d_ws, size_t ws_size,
                              hipStream_t stream) {
  (void)in_sizes; (void)n_in; (void)out_size;
  const float* Xk  = (const float*)d_in[0];
  const float* Pk  = (const float*)d_in[1];
  const float* lw  = (const float*)d_in[2];
  const float* lvw = (const float*)d_in[3];
  const int*   kp  = (const int*)d_in[4];

  float* Xo = (float*)d_out;        // X state in d_out[0:BTC]
  float* Po = Xo + NBTC;            // Pi state in d_out[BTC:2BTC]

  char* wp = (char*)d_ws;
  ushort* bX  = (ushort*)wp; wp += NBTC * sizeof(ushort);   // bf16 (R14)
  ushort* bPi = (ushort*)wp; wp += NBTC * sizeof(ushort);   // bf16 (R14)
  f16_t*  XnF = (f16_t*)wp;  wp += NBTC * sizeof(f16_t);
  ushort* Ehp = (ushort*)wp; wp += (size_t)Bn * NTRI * 16384 * sizeof(ushort);
  ushort* XTh = (ushort*)wp; wp += NBTC * sizeof(ushort);
  float*  zb  = (float*)wp;  wp += (size_t)Bn * Tn * sizeof(float);
  float*  aab = (float*)wp;  wp += (size_t)Bn * Tn * sizeof(float);
  float*  cst = (float*)wp;  wp += 256;
  const size_t need = (size_t)(wp - (char*)d_ws);
  if (ws_size < need) {
    fprintf(stderr, "[kernel] ws too small: %zu < %zu\n", ws_size, need);
    return;
  }

  const dim3 b256(256);
  const dim3 gLN(Bn * Tn / 4);               // wave-per-row, 4 rows/block
  const dim3 gXT(Tn / 64, Cn / 64, Bn);      // (32,12,4)
  const dim3 gZ(544);                        // XCD-aligned E-tile decode
  const dim3 gW(544);                        // same decode (no dead blocks)
  const dim3 gCore(768);                     // XCD-paired balanced swizzle
  const float rc = (float)cos(2.0), rs = (float)sin(2.0);   // theta = 2*XI*h

  prep_consts<<<1, 1, 0, stream>>>(kp, cst);

  // ---- Stage A: X-side = Xk, p = Pk (lam*Lam = 1) ----
  ln_sv_kernel<false, false><<<gLN, b256, 0, stream>>>(
      Xk, lw, XnF, zb, aab, Pk, cst, 6);
  xt_kernel<<<gXT, b256, 0, stream>>>((const ushort*)XnF, XTh);
  zpass_mfma<<<gZ, b256, 0, stream>>>(XnF, Ehp, zb);
  wbuild_kernel<<<gW, b256, 0, stream>>>(Ehp, zb, aab, cst, 6);
  corepass_mfma<0><<<gCore, b256, 0, stream>>>(Ehp, XTh, Pk, Po, cst, 0, 0,
      (float*)Xk, nullptr, (float*)bX, nullptr, zb, 6, rc, rs);

  // ---- Stage B: X-side = bX, Pi-side = Po; fused velupd-B + rotation ----
  ln_sv_kernel<true, false><<<gLN, b256, 0, stream>>>(
      bX, lw, XnF, zb, aab, Po, cst, 6);
  xt_kernel<<<gXT, b256, 0, stream>>>((const ushort*)XnF, XTh);
  zpass_mfma<<<gZ, b256, 0, stream>>>(XnF, Ehp, zb);
  wbuild_kernel<<<gW, b256, 0, stream>>>(Ehp, zb, aab, cst, 3);
  corepass_mfma<1><<<gCore, b256, 0, stream>>>(Ehp, XTh, Pk, (float*)bPi,
      cst, 0, 2, (float*)Xk, Po, (float*)bX, Xo, zb, 3, rc, rs);

  // ---- Stage C: X-side = bX (post-rotation), Pi-side = Po; velupd-C ----
  ln_sv_kernel<true, false><<<gLN, b256, 0, stream>>>(
      bX, lw, XnF, zb, aab, Po, cst, 6);
  xt_kernel<<<gXT, b256, 0, stream>>>((const ushort*)XnF, XTh);
  zpass_mfma<<<gZ, b256, 0, stream>>>(XnF, Ehp, zb);
  wbuild_kernel<<<gW, b256, 0, stream>>>(Ehp, zb, aab, cst, 3);
  corepass_mfma<2><<<gCore, b256, 0, stream>>>(Ehp, XTh, (float*)bPi,
      (float*)bPi, cst, 6, 2, Xo, Po, nullptr, nullptr, zb, 3, rc, rs);

  // ---- Stage D: X-side = Xo, p = lam_tk1*bPi ----
  ln_sv_kernel<false, true><<<gLN, b256, 0, stream>>>(
      Xo, lw, XnF, zb, aab, bPi, cst, 6);
  xt_kernel<<<gXT, b256, 0, stream>>>((const ushort*)XnF, XTh);
  zpass_mfma<<<gZ, b256, 0, stream>>>(XnF, Ehp, zb);
  wbuild_kernel<<<gW, b256, 0, stream>>>(Ehp, zb, aab, cst, 5);
  corepass_mfma<3><<<gCore, b256, 0, stream>>>(Ehp, XTh, Po, Po, cst, 6, 4,
      nullptr, nullptr, nullptr, nullptr, zb, 6, rc, rs);

  // ---- Final: Pk1 = LN(lam_tk1 * Pi) * ln_v_w (in place on Po) ----
  ln_f32_kernel<<<gLN, b256, 0, stream>>>(Po, lvw, Po, cst, 5);
}

// Round 15
// 504.464 us; speedup vs baseline: 1.1619x; 1.0328x over previous
//
#include <hip/hip_runtime.h>
#include <hip/hip_bf16.h>
#include <cstdio>
#include <cmath>

// Problem constants (B,T,C,NH fixed by the reference)
constexpr int   Bn = 4;
constexpr int   Tn = 2048;
constexpr int   Cn = 768;
constexpr float COEF  = 0.125f / 12.0f;   // SCALE / NH
constexpr float EPSZ  = 1e-8f;
constexpr float LNEPS = 1e-5f;
constexpr int   NTRI  = 136;              // triangular 128-tiles per batch
#define NBTC ((size_t)Bn * Tn * Cn)

typedef __bf16 bf16_t;
typedef _Float16 f16_t;
typedef bf16_t bf16x8 __attribute__((ext_vector_type(8)));
typedef f16_t  f16x8  __attribute__((ext_vector_type(8)));
typedef f16_t  f16x4  __attribute__((ext_vector_type(4)));
typedef float  f32x4  __attribute__((ext_vector_type(4)));
typedef ushort u16x8  __attribute__((ext_vector_type(8)));

// async global->LDS, 16B per lane. LDS dest is wave-uniform base + lane*16.
__device__ __forceinline__ void gload16(const void* g, void* l) {
  __builtin_amdgcn_global_load_lds(
      (const __attribute__((address_space(1))) unsigned int*)g,
      (__attribute__((address_space(3))) unsigned int*)l,
      16, 0, 0);
}

__device__ __forceinline__ ushort bf16_bits(float f) {
  bf16_t h = (bf16_t)f;
  return __builtin_bit_cast(ushort, h);
}
__device__ __forceinline__ float bits_to_f(ushort u) {
  return (float)__builtin_bit_cast(bf16_t, u);
}
__device__ __forceinline__ ushort f16bits_to_bf16bits(ushort u) {
  const float f = (float)__builtin_bit_cast(f16_t, u);
  return bf16_bits(f);
}

__device__ __forceinline__ float4 ld4f(const float* p) { return *(const float4*)p; }
__device__ __forceinline__ float4 ld4bf(const ushort* p) {
  const ushort4 u = *(const ushort4*)p;
  float4 r;
  r.x = bits_to_f(u.x); r.y = bits_to_f(u.y);
  r.z = bits_to_f(u.z); r.w = bits_to_f(u.w);
  return r;
}

__device__ __forceinline__ float wave_sum(float v) {
  #pragma unroll
  for (int off = 32; off > 0; off >>= 1) v += __shfl_xor(v, off);
  return v;
}

// sv from raw zpass row-sum: zf = max(sum/Tn, EPSZ); sv = a*ps^2/(zf^2+EPSZ)
__device__ __forceinline__ float sv_of(float zraw, float a, float ps2) {
  const float zf = fmaxf(zraw * (1.0f / Tn), EPSZ);
  return a * ps2 / (zf * zf + EPSZ);
}

// E-tile XCD-aligned decode (R10): id in [0,544): x=id&7, m=id>>3, b=m/17,
// u=m%17; u<=x: (it,jm)=(x,u) else (15-x, u-x-1). Equal work per class.
__device__ __forceinline__ void etile_decode(int id, int& b, int& it, int& jm) {
  const int x = id & 7;
  const int m = id >> 3;
  b = m / 17;
  const int u = m - b * 17;
  if (u <= x) { it = x;      jm = u; }
  else        { it = 15 - x; jm = u - x - 1; }
}

// cst[] indices: 0 Lam_tk, 1 lam_tk, 2 Lam_tbar, 3 lam_tbar, 4 Lam_tk1, 5 lam_tk1, 6 = 1.0
__global__ void prep_consts(const int* kp, float* cst) {
  if (threadIdx.x == 0 && blockIdx.x == 0) {
    float tk = 1.0f + (float)(*kp);
    float tb = tk + 0.5f;
    float t1 = tk + 1.0f;
    cst[0] = tk * tk * tk; cst[1] = 1.0f / cst[0];
    cst[2] = tb * tb * tb; cst[3] = 1.0f / cst[2];
    cst[4] = t1 * t1 * t1; cst[5] = 1.0f / cst[4];
    cst[6] = 1.0f;
  }
}

// Wave-per-row LayerNorm (R11), fp16-only output (R13), dtype-templated
// src/Pi (R14). LayerNorm of (alpha*src) -> fp16, PLUS |Pi row|^2 -> aab.
// Also zeroes zbuf[row] for zpass atomics. 4 rows/block, grid 2048.
template <bool SRC_BF, bool PI_BF>
__global__ void __launch_bounds__(256) ln_sv_kernel(
    const void* __restrict__ srcv_, const float* __restrict__ w,
    f16_t* __restrict__ outF,
    float* __restrict__ zbuf, float* __restrict__ aab,
    const void* __restrict__ Pisrc_,
    const float* __restrict__ cst, int alpha_idx) {
  const int lane = threadIdx.x & 63;
  const int row  = blockIdx.x * 4 + (threadIdx.x >> 6);
  const float alpha = cst[alpha_idx];
  const size_t base = (size_t)row * Cn;

  float4 v[3];
  float s = 0.f;
  #pragma unroll
  for (int q = 0; q < 3; ++q) {
    if (SRC_BF)
      v[q] = ld4bf((const ushort*)srcv_ + base + q * 256 + lane * 4);
    else
      v[q] = ld4f((const float*)srcv_ + base + q * 256 + lane * 4);
    v[q].x *= alpha; v[q].y *= alpha; v[q].z *= alpha; v[q].w *= alpha;
    s += v[q].x + v[q].y + v[q].z + v[q].w;
  }
  s = wave_sum(s);
  const float m = s * (1.0f / Cn);
  float vs = 0.f;
  #pragma unroll
  for (int q = 0; q < 3; ++q) {
    v[q].x -= m; v[q].y -= m; v[q].z -= m; v[q].w -= m;
    vs += v[q].x * v[q].x + v[q].y * v[q].y + v[q].z * v[q].z + v[q].w * v[q].w;
  }
  vs = wave_sum(vs);
  const float rstd = rsqrtf(vs * (1.0f / Cn) + LNEPS);

  #pragma unroll
  for (int q = 0; q < 3; ++q) {
    const float4 w4 = *(const float4*)&w[q * 256 + lane * 4];
    const float f0 = v[q].x * rstd * w4.x;
    const float f1 = v[q].y * rstd * w4.y;
    const float f2 = v[q].z * rstd * w4.z;
    const float f3 = v[q].w * rstd * w4.w;
    f16x4 hf = {(f16_t)f0, (f16_t)f1, (f16_t)f2, (f16_t)f3};
    *(f16x4*)&outF[base + q * 256 + lane * 4] = hf;
  }

  // |p|^2 reduction of the Pi-side row
  float a = 0.f;
  #pragma unroll
  for (int q = 0; q < 3; ++q) {
    float4 p4;
    if (PI_BF)
      p4 = ld4bf((const ushort*)Pisrc_ + base + q * 256 + lane * 4);
    else
      p4 = ld4f((const float*)Pisrc_ + base + q * 256 + lane * 4);
    a += p4.x * p4.x + p4.y * p4.y + p4.z * p4.z + p4.w * p4.w;
  }
  a = wave_sum(a);
  if (lane == 0) {
    aab[row] = a;
    zbuf[row] = 0.0f;
  }
}

// Transpose XnF(fp16) [b][s][c] -> XT [b][c][s] (bf16), converting
// fp16->bf16 on the load side (Xnb buffer eliminated).
// grid (Tn/64, Cn/64, Bn).
__global__ void __launch_bounds__(256) xt_kernel(
    const ushort* __restrict__ XhF, ushort* __restrict__ XT) {
  const int b = blockIdx.z;
  const int s0 = blockIdx.x * 64, c0 = blockIdx.y * 64;
  const int tid = threadIdx.x;
  __shared__ ushort t[64][68];
  const ushort* src = XhF + (size_t)b * Tn * Cn;
  ushort* dst = XT + (size_t)b * Cn * Tn;
  #pragma unroll
  for (int p = 0; p < 4; ++p) {
    const int r = p * 16 + (tid >> 4);
    const int c = (tid & 15) * 4;
    const ushort4 v = *(const ushort4*)&src[(size_t)(s0 + r) * Cn + c0 + c];
    ushort4 bv;
    bv.x = f16bits_to_bf16bits(v.x);
    bv.y = f16bits_to_bf16bits(v.y);
    bv.z = f16bits_to_bf16bits(v.z);
    bv.w = f16bits_to_bf16bits(v.w);
    *(ushort4*)&t[r][c] = bv;
  }
  __syncthreads();
  #pragma unroll
  for (int p = 0; p < 4; ++p) {
    const int cc = p * 16 + (tid >> 4);
    const int ss = (tid & 15) * 4;
    ushort4 o;
    o.x = t[ss + 0][cc]; o.y = t[ss + 1][cc];
    o.z = t[ss + 2][cc]; o.w = t[ss + 3][cc];
    *(ushort4*)&dst[(size_t)(c0 + cc) * Tn + s0 + ss] = o;
  }
}

// Causal gram, 128x128 tiles (R9), BK=64 / 32 KB LDS (R13), XCD-aligned
// 1D grid 544 (R10). E = exp(clip(S*COEF)) stored single-bf16 pair-packed.
// Row sums -> atomicAdd zbuf. block 256, acc[4][4].
__global__ void __launch_bounds__(256) zpass_mfma(
    const f16_t* __restrict__ XnF,
    ushort* __restrict__ Ehp, float* __restrict__ zbuf) {
  int b, it, jm;
  etile_decode(blockIdx.x, b, it, jm);
  const int l = it * (it + 1) / 2 + jm;
  const int t0 = it * 128, s0 = jm * 128;

  const int tid  = threadIdx.x;
  const int lane = tid & 63;
  const int wv   = tid >> 6;
  const int wr   = wv >> 1, wc = wv & 1;     // wave covers 64t x 64s
  const int quad = lane >> 4, l15 = lane & 15;

  const f16_t* XbF = XnF + (size_t)b * Tn * Cn;
  ushort* EhT = Ehp + ((size_t)b * NTRI + l) * 16384;

  __shared__ f16_t Af[2][128 * 32];   // 16 KB
  __shared__ f16_t Bf[2][128 * 32];   // 16 KB

  const int srow = lane >> 2;                // 0..15
  const int scol = (lane & 3) * 8;

  f32x4 acc[4][4] = {};

  for (int c0 = 0; c0 < Cn; c0 += 64) {
    __syncthreads();                 // protect LDS while prev chunk still read
    #pragma unroll
    for (int h = 0; h < 2; ++h) {
      const int cb = c0 + h * 32;
      const int rb0 = wv * 16, rb1 = 64 + wv * 16;
      gload16(XbF + (size_t)(t0 + rb0 + srow) * Cn + cb + scol, Af[h] + rb0 * 32);
      gload16(XbF + (size_t)(t0 + rb1 + srow) * Cn + cb + scol, Af[h] + rb1 * 32);
      gload16(XbF + (size_t)(s0 + rb0 + srow) * Cn + cb + scol, Bf[h] + rb0 * 32);
      gload16(XbF + (size_t)(s0 + rb1 + srow) * Cn + cb + scol, Bf[h] + rb1 * 32);
    }
    __syncthreads();                 // drain vmcnt + all slabs present

    #pragma unroll
    for (int h = 0; h < 2; ++h) {
      f16x8 af[4], bf[4];
      #pragma unroll
      for (int i = 0; i < 4; ++i)
        af[i] = *(const f16x8*)&Af[h][(wr * 64 + i * 16 + l15) * 32 + quad * 8];
      #pragma unroll
      for (int j = 0; j < 4; ++j)
        bf[j] = *(const f16x8*)&Bf[h][(wc * 64 + j * 16 + l15) * 32 + quad * 8];
      #pragma unroll
      for (int i = 0; i < 4; ++i)
        #pragma unroll
        for (int j = 0; j < 4; ++j)
          acc[i][j] = __builtin_amdgcn_mfma_f32_16x16x32_f16(af[i], bf[j], acc[i][j], 0, 0, 0);
    }
  }

  float zacc[4][4];
  #pragma unroll
  for (int i = 0; i < 4; ++i)
    #pragma unroll
    for (int r = 0; r < 4; ++r) zacc[i][r] = 0.0f;

  #pragma unroll
  for (int i = 0; i < 4; ++i) {
    #pragma unroll
    for (int j = 0; j < 4; ++j) {
      const int inCol = wc * 64 + j * 16 + l15;
      const int gcol  = s0 + inCol;
      #pragma unroll
      for (int r = 0; r < 4; ++r) {
        const int rowL = wr * 64 + i * 16 + quad * 4 + r;
        float sV = acc[i][j][r] * COEF;
        sV = fminf(fmaxf(sV, -60.f), 60.f);
        const float e = (gcol <= t0 + rowL) ? __expf(sV) : 0.f;
        const float pe = __shfl_xor(e, 1);
        if ((lane & 1) == 0) {
          const uint pk = (uint)bf16_bits(e) | ((uint)bf16_bits(pe) << 16);
          *(uint*)&EhT[rowL * 128 + inCol] = pk;
        }
        zacc[i][r] += e;
      }
    }
  }
  #pragma unroll
  for (int i = 0; i < 4; ++i)
    #pragma unroll
    for (int r = 0; r < 4; ++r) {
      float v = zacc[i][r];
      v += __shfl_xor(v, 1);
      v += __shfl_xor(v, 2);
      v += __shfl_xor(v, 4);
      v += __shfl_xor(v, 8);
      if (l15 == 0)
        atomicAdd(&zbuf[b * Tn + t0 + wr * 64 + i * 16 + quad * 4 + r], v);
    }
}

// In-place W-build: E[t,s] *= (sv[t] + sv[s] - 2), packed single-bf16 tiles.
// sv computed inline from raw zbuf + aab (R8). 1D grid 544, XCD-aligned
// decode (R10).
__global__ void __launch_bounds__(256) wbuild_kernel(
    ushort* __restrict__ Ehp, const float* __restrict__ zbuf,
    const float* __restrict__ aab, const float* __restrict__ cst, int ps_idx) {
  int b, it, st;
  etile_decode(blockIdx.x, b, it, st);
  const int tri = it * (it + 1) / 2 + st;
  ushort* EhT = Ehp + ((size_t)b * NTRI + tri) * 16384;
  const float ps = cst[ps_idx];
  const float ps2 = ps * ps;

  const int tid = threadIdx.x;
  __shared__ float scol[128];
  if (tid < 128) {
    const int i = b * Tn + st * 128 + tid;
    scol[tid] = sv_of(zbuf[i], aab[i], ps2);
  }
  __syncthreads();

  const int r  = tid >> 1;            // 0..127
  const int ch = (tid & 1) * 64;      // col half
  const int irow = b * Tn + it * 128 + r;
  const float svt2 = sv_of(zbuf[irow], aab[irow], ps2) - 2.0f;
  const int base = r * 128 + ch;
  #pragma unroll
  for (int v = 0; v < 8; ++v) {
    u16x8 h8 = *(const u16x8*)&EhT[base + v * 8];
    u16x8 nh;
    #pragma unroll
    for (int q = 0; q < 8; ++q) {
      const float w = bits_to_f(h8[q]) * (svt2 + scol[ch + v * 8 + q]);
      nh[q] = bf16_bits(w);
    }
    *(u16x8*)&EhT[base + v * 8] = nh;
  }
}

// core GEMM + fused elementwise epilogues. K=64 double-slab chunks, R0
// 2-barrier loop, 128t x 64c tile, grid 768. R7 XCD-paired balanced
// swizzle. z finalization inline (R8) — zb holds RAW row sums.
// R14: bX (eC), bPi (MODE1 dst / MODE2 src+dst) bf16.
// R15: intermediate momentum Pw bf16 — MODE0 dst, MODE1 eB r/w,
// MODE2 eB read, MODE3 src+dst are all bf16 now.
template <int MODE>
__global__ void __launch_bounds__(256) corepass_mfma(
    const ushort* __restrict__ Whp, const ushort* __restrict__ XT,
    const float* src, float* dst,
    const float* __restrict__ cst, int ss_idx, int lam_idx,
    float* eA, float* eB, float* eC, float* eD,
    const float* __restrict__ zb, int vel_idx, float rc, float rs) {
  const int id = blockIdx.x;
  const int x  = id & 7;                 // XCD class
  const int n  = id >> 3;                // 0..95
  const int k  = n / 12;                 // strip 0..7 within class
  const int ic = n - k * 12;             // 0..11
  const int b  = k & 3;
  const int it = (k >> 2) ? x : (15 - x);   // big strips first
  const int t0 = it * 128, c0 = ic * 64;

  const int tid  = threadIdx.x;
  const int lane = tid & 63;
  const int wv   = tid >> 6;
  const int wr   = wv >> 1, wc = wv & 1;   // wave covers 64t x 32c
  const int quad = lane >> 4, l15 = lane & 15;

  const ushort* WhB = Whp + (size_t)b * NTRI * 16384;
  const ushort* XTb = XT + (size_t)b * Cn * Tn;

  __shared__ ushort Ah[2][128 * 32];   // W slabs  (16 KB)
  __shared__ ushort Bh[2][64 * 32];    // X^T slabs (8 KB)

  const int srow = lane >> 2;
  const int scol = (lane & 3) * 8;
  const int triBase = it * (it + 1) / 2;

  f32x4 acc[4][2] = {};
  const int chunks = (it + 1) * 2;           // 64-k chunks
  for (int kc = 0; kc < chunks; ++kc) {
    const int ss0 = kc * 64;
    const int stile = kc >> 1, soff = (kc & 1) * 64;
    const ushort* tileB = WhB + (size_t)(triBase + stile) * 16384 + soff;

    __syncthreads();                 // prev chunk's LDS reads done
    #pragma unroll
    for (int h = 0; h < 2; ++h) {
      const ushort* tileH = tileB + h * 32;
      const int rb0 = wv * 16, rb1 = 64 + wv * 16;
      gload16(tileH + (size_t)(rb0 + srow) * 128 + scol, Ah[h] + rb0 * 32);
      gload16(tileH + (size_t)(rb1 + srow) * 128 + scol, Ah[h] + rb1 * 32);
      gload16(XTb + (size_t)(c0 + wv * 16 + srow) * Tn + ss0 + h * 32 + scol,
              Bh[h] + wv * 16 * 32);
    }
    __syncthreads();                 // drain vmcnt

    #pragma unroll
    for (int h = 0; h < 2; ++h) {
      bf16x8 ah[4], bh[2];
      #pragma unroll
      for (int i = 0; i < 4; ++i)
        ah[i] = *(const bf16x8*)&Ah[h][(wr * 64 + i * 16 + l15) * 32 + quad * 8];
      #pragma unroll
      for (int j = 0; j < 2; ++j)
        bh[j] = *(const bf16x8*)&Bh[h][(wc * 32 + j * 16 + l15) * 32 + quad * 8];
      #pragma unroll
      for (int i = 0; i < 4; ++i)
        #pragma unroll
        for (int j = 0; j < 2; ++j)
          acc[i][j] = __builtin_amdgcn_mfma_f32_16x16x32_bf16(ah[i], bh[j], acc[i][j], 0, 0, 0);
    }
  }

  const float coef = 0.5f * cst[lam_idx] * (1.0f / (2.0f * Tn));
  const float ssc = cst[ss_idx];
  const float vs = 0.5f * cst[vel_idx];
  #pragma unroll
  for (int i = 0; i < 4; ++i) {
    #pragma unroll
    for (int j = 0; j < 2; ++j) {
      const int col = c0 + wc * 32 + j * 16 + l15;
      #pragma unroll
      for (int r = 0; r < 4; ++r) {
        const int row = t0 + wr * 64 + i * 16 + quad * 4 + r;
        const size_t off = ((size_t)b * Tn + row) * Cn + col;
        // src: bf16 in MODE2 (bPi) and MODE3 (Pw); fp32 otherwise (Pk)
        const float srcv = (MODE == 2 || MODE == 3)
            ? bits_to_f(((const ushort*)src)[off]) : src[off];
        const float d = srcv * ssc + coef * acc[i][j][r];
        if (MODE == 0) {
          const float z = fmaxf(zb[b * Tn + row] * (1.0f / Tn), EPSZ);
          ((ushort*)dst)[off] = bf16_bits(d);             // Pw (bf16)
          ((ushort*)eC)[off] = bf16_bits(eA[off] + vs * srcv / z);  // bX (bf16)
        } else if (MODE == 1) {
          const float z = fmaxf(zb[b * Tn + row] * (1.0f / Tn), EPSZ);
          const float po = bits_to_f(((const ushort*)eB)[off]);     // Pw (bf16)
          const float xo = eA[off] + vs * po / z;
          const float bx = bits_to_f(((const ushort*)eC)[off]);     // bX (bf16)
          const float dX = xo - bx, dPi = po - d;
          const float sX = xo + bx, sPi = po + d;
          eD[off] = 0.5f * (sX + rc * dX + rs * dPi);               // Xo (f32)
          ((ushort*)eB)[off] = bf16_bits(0.5f * (sPi - rs * dX + rc * dPi)); // Pw
          ((ushort*)eC)[off] = bf16_bits(0.5f * (sX - rc * dX - rs * dPi)); // bX
          ((ushort*)dst)[off] = bf16_bits(0.5f * (sPi + rs * dX - rc * dPi)); // bPi
        } else if (MODE == 2) {
          const float z = fmaxf(zb[b * Tn + row] * (1.0f / Tn), EPSZ);
          ((ushort*)dst)[off] = bf16_bits(d);             // bPi (bf16)
          const float pw = bits_to_f(((const ushort*)eB)[off]);     // Pw (bf16)
          eA[off] = eA[off] + vs * pw / z;                // Xo (f32, final)
        } else {
          ((ushort*)dst)[off] = bf16_bits(d);             // Pw (bf16)
        }
      }
    }
  }
}

// Wave-per-row final LayerNorm (R11). R15: bf16-src template (reads the
// bf16 Pw intermediate, writes fp32 output).
template <bool SRC_BF>
__global__ void __launch_bounds__(256) ln_f32_kernel(
    const void* __restrict__ src_, const float* __restrict__ w,
    float* dst, const float* __restrict__ cst, int alpha_idx) {
  const int lane = threadIdx.x & 63;
  const int row  = blockIdx.x * 4 + (threadIdx.x >> 6);
  const float alpha = cst[alpha_idx];
  const size_t base = (size_t)row * Cn;

  float4 v[3];
  float s = 0.f;
  #pragma unroll
  for (int q = 0; q < 3; ++q) {
    if (SRC_BF)
      v[q] = ld4bf((const ushort*)src_ + base + q * 256 + lane * 4);
    else
      v[q] = ld4f((const float*)src_ + base + q * 256 + lane * 4);
    v[q].x *= alpha; v[q].y *= alpha; v[q].z *= alpha; v[q].w *= alpha;
    s += v[q].x + v[q].y + v[q].z + v[q].w;
  }
  s = wave_sum(s);
  const float m = s * (1.0f / Cn);
  float vs = 0.f;
  #pragma unroll
  for (int q = 0; q < 3; ++q) {
    v[q].x -= m; v[q].y -= m; v[q].z -= m; v[q].w -= m;
    vs += v[q].x * v[q].x + v[q].y * v[q].y + v[q].z * v[q].z + v[q].w * v[q].w;
  }
  vs = wave_sum(vs);
  const float rstd = rsqrtf(vs * (1.0f / Cn) + LNEPS);

  float* y = dst + base;
  #pragma unroll
  for (int q = 0; q < 3; ++q) {
    const float4 w4 = *(const float4*)&w[q * 256 + lane * 4];
    float4 o;
    o.x = v[q].x * rstd * w4.x;
    o.y = v[q].y * rstd * w4.y;
    o.z = v[q].z * rstd * w4.z;
    o.w = v[q].w * rstd * w4.w;
    *(float4*)&y[q * 256 + lane * 4] = o;
  }
}

extern "C" void kernel_launch(void* const* d_in, const int* in_sizes, int n_in,
                              void* d_out, int out_size, void* d_ws, size_t ws_size,
                              hipStream_t stream) {
  (void)in_sizes; (void)n_in; (void)out_size;
  const float* Xk  = (const float*)d_in[0];
  const float* Pk  = (const float*)d_in[1];
  const float* lw  = (const float*)d_in[2];
  const float* lvw = (const float*)d_in[3];
  const int*   kp  = (const int*)d_in[4];

  float* Xo = (float*)d_out;        // X state in d_out[0:BTC]
  float* Po = Xo + NBTC;            // final Pk1 output in d_out[BTC:2BTC]

  char* wp = (char*)d_ws;
  ushort* bX  = (ushort*)wp; wp += NBTC * sizeof(ushort);   // bf16 (R14)
  ushort* bPi = (ushort*)wp; wp += NBTC * sizeof(ushort);   // bf16 (R14)
  ushort* Pw  = (ushort*)wp; wp += NBTC * sizeof(ushort);   // bf16 Pi (R15)
  f16_t*  XnF = (f16_t*)wp;  wp += NBTC * sizeof(f16_t);
  ushort* Ehp = (ushort*)wp; wp += (size_t)Bn * NTRI * 16384 * sizeof(ushort);
  ushort* XTh = (ushort*)wp; wp += NBTC * sizeof(ushort);
  float*  zb  = (float*)wp;  wp += (size_t)Bn * Tn * sizeof(float);
  float*  aab = (float*)wp;  wp += (size_t)Bn * Tn * sizeof(float);
  float*  cst = (float*)wp;  wp += 256;
  const size_t need = (size_t)(wp - (char*)d_ws);
  if (ws_size < need) {
    fprintf(stderr, "[kernel] ws too small: %zu < %zu\n", ws_size, need);
    return;
  }

  const dim3 b256(256);
  const dim3 gLN(Bn * Tn / 4);               // wave-per-row, 4 rows/block
  const dim3 gXT(Tn / 64, Cn / 64, Bn);      // (32,12,4)
  const dim3 gZ(544);                        // XCD-aligned E-tile decode
  const dim3 gW(544);                        // same decode (no dead blocks)
  const dim3 gCore(768);                     // XCD-paired balanced swizzle
  const float rc = (float)cos(2.0), rs = (float)sin(2.0);   // theta = 2*XI*h

  prep_consts<<<1, 1, 0, stream>>>(kp, cst);

  // ---- Stage A: X-side = Xk, p = Pk (lam*Lam = 1) ----
  ln_sv_kernel<false, false><<<gLN, b256, 0, stream>>>(
      Xk, lw, XnF, zb, aab, Pk, cst, 6);
  xt_kernel<<<gXT, b256, 0, stream>>>((const ushort*)XnF, XTh);
  zpass_mfma<<<gZ, b256, 0, stream>>>(XnF, Ehp, zb);
  wbuild_kernel<<<gW, b256, 0, stream>>>(Ehp, zb, aab, cst, 6);
  corepass_mfma<0><<<gCore, b256, 0, stream>>>(Ehp, XTh, Pk, (float*)Pw,
      cst, 0, 0, (float*)Xk, nullptr, (float*)bX, nullptr, zb, 6, rc, rs);

  // ---- Stage B: X-side = bX, Pi-side = Pw; fused velupd-B + rotation ----
  ln_sv_kernel<true, true><<<gLN, b256, 0, stream>>>(
      bX, lw, XnF, zb, aab, Pw, cst, 6);
  xt_kernel<<<gXT, b256, 0, stream>>>((const ushort*)XnF, XTh);
  zpass_mfma<<<gZ, b256, 0, stream>>>(XnF, Ehp, zb);
  wbuild_kernel<<<gW, b256, 0, stream>>>(Ehp, zb, aab, cst, 3);
  corepass_mfma<1><<<gCore, b256, 0, stream>>>(Ehp, XTh, Pk, (float*)bPi,
      cst, 0, 2, (float*)Xk, (float*)Pw, (float*)bX, Xo, zb, 3, rc, rs);

  // ---- Stage C: X-side = bX (post-rotation), Pi-side = Pw; velupd-C ----
  ln_sv_kernel<true, true><<<gLN, b256, 0, stream>>>(
      bX, lw, XnF, zb, aab, Pw, cst, 6);
  xt_kernel<<<gXT, b256, 0, stream>>>((const ushort*)XnF, XTh);
  zpass_mfma<<<gZ, b256, 0, stream>>>(XnF, Ehp, zb);
  wbuild_kernel<<<gW, b256, 0, stream>>>(Ehp, zb, aab, cst, 3);
  corepass_mfma<2><<<gCore, b256, 0, stream>>>(Ehp, XTh, (float*)bPi,
      (float*)bPi, cst, 6, 2, Xo, (float*)Pw, nullptr, nullptr, zb, 3, rc, rs);

  // ---- Stage D: X-side = Xo, p = lam_tk1*bPi ----
  ln_sv_kernel<false, true><<<gLN, b256, 0, stream>>>(
      Xo, lw, XnF, zb, aab, bPi, cst, 6);
  xt_kernel<<<gXT, b256, 0, stream>>>((const ushort*)XnF, XTh);
  zpass_mfma<<<gZ, b256, 0, stream>>>(XnF, Ehp, zb);
  wbuild_kernel<<<gW, b256, 0, stream>>>(Ehp, zb, aab, cst, 5);
  corepass_mfma<3><<<gCore, b256, 0, stream>>>(Ehp, XTh, (float*)Pw,
      (float*)Pw, cst, 6, 4, nullptr, nullptr, nullptr, nullptr, zb, 6, rc, rs);

  // ---- Final: Pk1 = LN(lam_tk1 * Pw) * ln_v_w -> Po (fp32 output) ----
  ln_f32_kernel<true><<<gLN, b256, 0, stream>>>(Pw, lvw, Po, cst, 5);
}